// Round 1
// baseline (1720.426 us; speedup 1.0000x reference)
//
#include <hip/hip_runtime.h>
#include <math.h>

#define B_ 2
#define S_ 2048
#define D_ 1024
#define H_ 16
#define E_ 64
// M = B_*S_ = 4096 rows for the projection GEMMs

// ---------------------------------------------------------------------------
// Shared micro-kernel piece: 4x4 FMA rank-1 update
// ---------------------------------------------------------------------------
__device__ __forceinline__ void fma4x4(float acc[4][4], float a0, float a1,
                                       float a2, float a3, float4 b) {
    acc[0][0] += a0 * b.x; acc[0][1] += a0 * b.y; acc[0][2] += a0 * b.z; acc[0][3] += a0 * b.w;
    acc[1][0] += a1 * b.x; acc[1][1] += a1 * b.y; acc[1][2] += a1 * b.z; acc[1][3] += a1 * b.w;
    acc[2][0] += a2 * b.x; acc[2][1] += a2 * b.y; acc[2][2] += a2 * b.z; acc[2][3] += a2 * b.w;
    acc[3][0] += a3 * b.x; acc[3][1] += a3 * b.y; acc[3][2] += a3 * b.z; acc[3][3] += a3 * b.w;
}

// ---------------------------------------------------------------------------
// Kernel 1: per-head QKV projection.  X[4096,1024] x W[H,D,E] + b[H,E]
//           -> out[B,H,S,E].  One 64-col tile == one head (E=64).
// grid (N/64=16, M/64=64), block 256.
// ---------------------------------------------------------------------------
__global__ __launch_bounds__(256) void qkv_proj_kernel(
    const float* __restrict__ X, const float* __restrict__ W,
    const float* __restrict__ bias, float* __restrict__ out) {
    __shared__ float As[64][17];   // As[m][k], pad kills transpose-store conflicts
    __shared__ float Bs[16][68];   // Bs[k][n], 272B row stride keeps float4 align
    const int t = threadIdx.x;
    const int tx = t & 15, ty = t >> 4;
    const int m0 = ty * 4, n0 = tx * 4;
    const int gm0 = blockIdx.y * 64;
    const int h = blockIdx.x;  // head == n-tile

    float acc[4][4] = {};
    for (int k0 = 0; k0 < D_; k0 += 16) {
        for (int i = t; i < 64 * 16; i += 256) {
            int m_ = i >> 4, k_ = i & 15;
            As[m_][k_] = X[(gm0 + m_) * D_ + k0 + k_];
        }
        for (int i = t; i < 16 * 64; i += 256) {
            int k_ = i >> 6, e_ = i & 63;
            Bs[k_][e_] = W[h * (D_ * E_) + (k0 + k_) * E_ + e_];
        }
        __syncthreads();
#pragma unroll
        for (int kk = 0; kk < 16; ++kk) {
            float a0 = As[m0 + 0][kk], a1 = As[m0 + 1][kk];
            float a2 = As[m0 + 2][kk], a3 = As[m0 + 3][kk];
            float4 b4 = *reinterpret_cast<const float4*>(&Bs[kk][n0]);
            fma4x4(acc, a0, a1, a2, a3, b4);
        }
        __syncthreads();
    }
    float4 bb = *reinterpret_cast<const float4*>(&bias[h * E_ + n0]);
#pragma unroll
    for (int i2 = 0; i2 < 4; ++i2) {
        int m = gm0 + m0 + i2;
        int b = m >> 11, s = m & 2047;
        float4 r;
        r.x = acc[i2][0] + bb.x; r.y = acc[i2][1] + bb.y;
        r.z = acc[i2][2] + bb.z; r.w = acc[i2][3] + bb.w;
        *reinterpret_cast<float4*>(
            &out[((size_t)(b * H_ + h) * S_ + s) * E_ + n0]) = r;
    }
}

// ---------------------------------------------------------------------------
// Kernel 2: scores = (Q Kᵀ)/8 with causal mask, written into the weights
//           output buffer (masked entries written as exact 0).
// grid (S/64=32 ktiles, S/64=32 qtiles, B*H=32), block 256.
// ---------------------------------------------------------------------------
__global__ __launch_bounds__(256) void scores_kernel(
    const float* __restrict__ qh, const float* __restrict__ kh,
    float* __restrict__ wts) {
    const int z = blockIdx.z;
    const int qt = blockIdx.y, kt = blockIdx.x;
    const int t = threadIdx.x;
    const int tx = t & 15, ty = t >> 4;
    const int m0 = ty * 4, n0 = tx * 4;
    const int q0 = qt * 64, kc0 = kt * 64;
    float* wz = wts + (size_t)z * S_ * S_;

    if (kt > qt) {  // fully-masked tile: write zeros (block-uniform branch)
        float4 zero = make_float4(0.f, 0.f, 0.f, 0.f);
#pragma unroll
        for (int i2 = 0; i2 < 4; ++i2)
            *reinterpret_cast<float4*>(
                &wz[(size_t)(q0 + m0 + i2) * S_ + kc0 + n0]) = zero;
        return;
    }

    const float* Q = qh + (size_t)z * S_ * E_;
    const float* K = kh + (size_t)z * S_ * E_;
    __shared__ float Qs[64][17];
    __shared__ float Ks[16][68];
    float acc[4][4] = {};
    for (int e0 = 0; e0 < E_; e0 += 16) {
        for (int i = t; i < 64 * 16; i += 256) {
            int m_ = i >> 4, e_ = i & 15;
            Qs[m_][e_] = Q[(q0 + m_) * E_ + e0 + e_];
        }
        for (int i = t; i < 64 * 16; i += 256) {
            int kcol = i >> 4, e_ = i & 15;
            Ks[e_][kcol] = K[(kc0 + kcol) * E_ + e0 + e_];
        }
        __syncthreads();
#pragma unroll
        for (int kk = 0; kk < 16; ++kk) {
            float a0 = Qs[m0 + 0][kk], a1 = Qs[m0 + 1][kk];
            float a2 = Qs[m0 + 2][kk], a3 = Qs[m0 + 3][kk];
            float4 b4 = *reinterpret_cast<const float4*>(&Ks[kk][n0]);
            fma4x4(acc, a0, a1, a2, a3, b4);
        }
        __syncthreads();
    }
#pragma unroll
    for (int i2 = 0; i2 < 4; ++i2) {
        int q = q0 + m0 + i2;
        float4 r;
        r.x = (kc0 + n0 + 0 <= q) ? acc[i2][0] * 0.125f : 0.f;
        r.y = (kc0 + n0 + 1 <= q) ? acc[i2][1] * 0.125f : 0.f;
        r.z = (kc0 + n0 + 2 <= q) ? acc[i2][2] * 0.125f : 0.f;
        r.w = (kc0 + n0 + 3 <= q) ? acc[i2][3] * 0.125f : 0.f;
        *reinterpret_cast<float4*>(&wz[(size_t)q * S_ + kc0 + n0]) = r;
    }
}

// ---------------------------------------------------------------------------
// Kernel 3: in-place row softmax over valid prefix [0..q] of each row.
// grid (B*H*S = 65536), block 256; each thread owns 8 strided elements.
// ---------------------------------------------------------------------------
__global__ __launch_bounds__(256) void softmax_kernel(float* __restrict__ wts) {
    const int row = blockIdx.x;
    const int z = row >> 11;        // / S_
    const int q = row & (S_ - 1);   // % S_
    float* w = wts + (size_t)z * S_ * S_ + (size_t)q * S_;
    const int t = threadIdx.x;

    float v[8];
    float mx = -INFINITY;
#pragma unroll
    for (int j = 0; j < 8; ++j) {
        int idx = t + j * 256;
        v[j] = (idx <= q) ? w[idx] : -INFINITY;
        mx = fmaxf(mx, v[j]);
    }
    __shared__ float sred[256];
    sred[t] = mx;
    __syncthreads();
    for (int s = 128; s > 0; s >>= 1) {
        if (t < s) sred[t] = fmaxf(sred[t], sred[t + s]);
        __syncthreads();
    }
    mx = sred[0];
    __syncthreads();

    float sum = 0.f;
#pragma unroll
    for (int j = 0; j < 8; ++j) {
        int idx = t + j * 256;
        float e = (idx <= q) ? __expf(v[j] - mx) : 0.f;
        v[j] = e;
        sum += e;
    }
    sred[t] = sum;
    __syncthreads();
    for (int s = 128; s > 0; s >>= 1) {
        if (t < s) sred[t] += sred[t + s];
        __syncthreads();
    }
    const float inv = 1.f / sred[0];
#pragma unroll
    for (int j = 0; j < 8; ++j) {
        int idx = t + j * 256;
        if (idx <= q) w[idx] = v[j] * inv;
    }
}

// ---------------------------------------------------------------------------
// Kernel 4: attn = weights @ V   (per (b,h): [S,S_valid] x [S,E] -> [S,E])
// grid (qtile=32, 1, B*H=32), block 256.  K-loop stops after diagonal block
// (upper triangle of weights is exactly 0).
// ---------------------------------------------------------------------------
__global__ __launch_bounds__(256) void pv_kernel(
    const float* __restrict__ wts, const float* __restrict__ vh,
    float* __restrict__ attn) {
    const int z = blockIdx.z, qt = blockIdx.x;
    const int t = threadIdx.x;
    const int tx = t & 15, ty = t >> 4;
    const int m0 = ty * 4, n0 = tx * 4;
    const int q0 = qt * 64;
    const float* wz = wts + (size_t)z * S_ * S_;
    const float* vz = vh + (size_t)z * S_ * E_;
    __shared__ float Ws[64][17];
    __shared__ float Vs[16][68];
    float acc[4][4] = {};
    const int kend = (qt + 1) * 64;
    for (int k0 = 0; k0 < kend; k0 += 16) {
        for (int i = t; i < 64 * 16; i += 256) {
            int m_ = i >> 4, k_ = i & 15;
            Ws[m_][k_] = wz[(size_t)(q0 + m_) * S_ + k0 + k_];
        }
        for (int i = t; i < 16 * 64; i += 256) {
            int k_ = i >> 6, e_ = i & 63;
            Vs[k_][e_] = vz[(k0 + k_) * E_ + e_];
        }
        __syncthreads();
#pragma unroll
        for (int kk = 0; kk < 16; ++kk) {
            float a0 = Ws[m0 + 0][kk], a1 = Ws[m0 + 1][kk];
            float a2 = Ws[m0 + 2][kk], a3 = Ws[m0 + 3][kk];
            float4 b4 = *reinterpret_cast<const float4*>(&Vs[kk][n0]);
            fma4x4(acc, a0, a1, a2, a3, b4);
        }
        __syncthreads();
    }
#pragma unroll
    for (int i2 = 0; i2 < 4; ++i2) {
        float4 r;
        r.x = acc[i2][0]; r.y = acc[i2][1]; r.z = acc[i2][2]; r.w = acc[i2][3];
        *reinterpret_cast<float4*>(
            &attn[(size_t)z * S_ * E_ + (size_t)(q0 + m0 + i2) * E_ + n0]) = r;
    }
}

// ---------------------------------------------------------------------------
// Kernel 5: out = concat(attn) @ Wo + bo.   concat[m][k] = attn[b, k/64, s, k%64]
// grid (16, 64), block 256.
// ---------------------------------------------------------------------------
__global__ __launch_bounds__(256) void outproj_kernel(
    const float* __restrict__ attn, const float* __restrict__ Wo,
    const float* __restrict__ bo, float* __restrict__ out) {
    __shared__ float As[64][17];
    __shared__ float Bs[16][68];
    const int t = threadIdx.x;
    const int tx = t & 15, ty = t >> 4;
    const int m0 = ty * 4, n0 = tx * 4;
    const int gn0 = blockIdx.x * 64;
    const int gm0 = blockIdx.y * 64;

    float acc[4][4] = {};
    for (int k0 = 0; k0 < D_; k0 += 16) {
        for (int i = t; i < 64 * 16; i += 256) {
            int m_ = i >> 4, k_ = i & 15;
            int kcol = k0 + k_;
            int h = kcol >> 6, e = kcol & 63;
            int m = gm0 + m_;
            int b = m >> 11, s = m & 2047;
            As[m_][k_] = attn[((size_t)(b * H_ + h) * S_ + s) * E_ + e];
        }
        for (int i = t; i < 16 * 64; i += 256) {
            int k_ = i >> 6, n_ = i & 63;
            Bs[k_][n_] = Wo[(k0 + k_) * D_ + gn0 + n_];
        }
        __syncthreads();
#pragma unroll
        for (int kk = 0; kk < 16; ++kk) {
            float a0 = As[m0 + 0][kk], a1 = As[m0 + 1][kk];
            float a2 = As[m0 + 2][kk], a3 = As[m0 + 3][kk];
            float4 b4 = *reinterpret_cast<const float4*>(&Bs[kk][n0]);
            fma4x4(acc, a0, a1, a2, a3, b4);
        }
        __syncthreads();
    }
    float4 bb = *reinterpret_cast<const float4*>(&bo[gn0 + n0]);
#pragma unroll
    for (int i2 = 0; i2 < 4; ++i2) {
        int m = gm0 + m0 + i2;
        float4 r;
        r.x = acc[i2][0] + bb.x; r.y = acc[i2][1] + bb.y;
        r.z = acc[i2][2] + bb.z; r.w = acc[i2][3] + bb.w;
        *reinterpret_cast<float4*>(&out[(size_t)m * D_ + gn0 + n0]) = r;
    }
}

// ---------------------------------------------------------------------------
extern "C" void kernel_launch(void* const* d_in, const int* in_sizes, int n_in,
                              void* d_out, int out_size, void* d_ws,
                              size_t ws_size, hipStream_t stream) {
    const float* q = (const float*)d_in[0];
    const float* k = (const float*)d_in[1];
    const float* v = (const float*)d_in[2];
    const float* Wq = (const float*)d_in[3];
    const float* bq = (const float*)d_in[4];
    const float* Wk = (const float*)d_in[5];
    const float* bk = (const float*)d_in[6];
    const float* Wv = (const float*)d_in[7];
    const float* bv = (const float*)d_in[8];
    const float* Wo = (const float*)d_in[9];
    const float* bo = (const float*)d_in[10];

    float* out = (float*)d_out;                       // [B,S,D]
    float* wts = out + (size_t)B_ * S_ * D_;          // [B,H,S,S]

    float* qh = (float*)d_ws;                         // [B,H,S,E]
    float* kh = qh + (size_t)B_ * H_ * S_ * E_;
    float* vh = kh + (size_t)B_ * H_ * S_ * E_;
    float* attn = qh;  // reuse qh region after scores are computed

    dim3 blk(256);
    qkv_proj_kernel<<<dim3(16, 64, 1), blk, 0, stream>>>(q, Wq, bq, qh);
    qkv_proj_kernel<<<dim3(16, 64, 1), blk, 0, stream>>>(k, Wk, bk, kh);
    qkv_proj_kernel<<<dim3(16, 64, 1), blk, 0, stream>>>(v, Wv, bv, vh);
    scores_kernel<<<dim3(32, 32, 32), blk, 0, stream>>>(qh, kh, wts);
    softmax_kernel<<<dim3(B_ * H_ * S_, 1, 1), blk, 0, stream>>>(wts);
    pv_kernel<<<dim3(32, 1, 32), blk, 0, stream>>>(wts, vh, attn);
    outproj_kernel<<<dim3(16, 64, 1), blk, 0, stream>>>(attn, Wo, bo, out);
}

// Round 2
// 1055.365 us; speedup vs baseline: 1.6302x; 1.6302x over previous
//
#include <hip/hip_runtime.h>
#include <math.h>

#define B_ 2
#define S_ 2048
#define D_ 1024
#define H_ 16
#define E_ 64
#define Z_ (B_ * H_)

typedef short short8 __attribute__((ext_vector_type(8)));
typedef float f32x4 __attribute__((ext_vector_type(4)));

__device__ __forceinline__ ushort f2bf(float x) {
    union { float f; unsigned u; } c; c.f = x;
    unsigned r = (c.u + 0x7FFFu + ((c.u >> 16) & 1u)) >> 16;
    return (ushort)r;
}

__device__ __forceinline__ f32x4 mfma16(short8 a, short8 b, f32x4 c) {
    return __builtin_amdgcn_mfma_f32_16x16x32_bf16(a, b, c, 0, 0, 0);
}

// ---------------------------------------------------------------------------
// 4x4 FMA rank-1 update (fp32 tiled GEMM micro-kernel, kept for proj/outproj)
// ---------------------------------------------------------------------------
__device__ __forceinline__ void fma4x4(float acc[4][4], float a0, float a1,
                                       float a2, float a3, float4 b) {
    acc[0][0] += a0 * b.x; acc[0][1] += a0 * b.y; acc[0][2] += a0 * b.z; acc[0][3] += a0 * b.w;
    acc[1][0] += a1 * b.x; acc[1][1] += a1 * b.y; acc[1][2] += a1 * b.z; acc[1][3] += a1 * b.w;
    acc[2][0] += a2 * b.x; acc[2][1] += a2 * b.y; acc[2][2] += a2 * b.z; acc[2][3] += a2 * b.w;
    acc[3][0] += a3 * b.x; acc[3][1] += a3 * b.y; acc[3][2] += a3 * b.z; acc[3][3] += a3 * b.w;
}

// ---------------------------------------------------------------------------
// QKV projection -> bf16.  VMODE 0: out[z][s][64]   VMODE 1: out[z][64][s]
// grid (16 heads, 64 mtiles), block 256.
// ---------------------------------------------------------------------------
template <int VMODE>
__global__ __launch_bounds__(256) void qkv_proj_bf16_kernel(
    const float* __restrict__ X, const float* __restrict__ W,
    const float* __restrict__ bias, ushort* __restrict__ out) {
    __shared__ float As[64][17];
    __shared__ float Bs[16][68];
    const int t = threadIdx.x;
    const int tx = t & 15, ty = t >> 4;
    const int m0 = ty * 4, n0 = tx * 4;
    const int gm0 = blockIdx.y * 64;
    const int h = blockIdx.x;

    float acc[4][4] = {};
    for (int k0 = 0; k0 < D_; k0 += 16) {
        for (int i = t; i < 64 * 16; i += 256) {
            int m_ = i >> 4, k_ = i & 15;
            As[m_][k_] = X[(gm0 + m_) * D_ + k0 + k_];
        }
        for (int i = t; i < 16 * 64; i += 256) {
            int k_ = i >> 6, e_ = i & 63;
            Bs[k_][e_] = W[h * (D_ * E_) + (k0 + k_) * E_ + e_];
        }
        __syncthreads();
#pragma unroll
        for (int kk = 0; kk < 16; ++kk) {
            float a0 = As[m0 + 0][kk], a1 = As[m0 + 1][kk];
            float a2 = As[m0 + 2][kk], a3 = As[m0 + 3][kk];
            float4 b4 = *reinterpret_cast<const float4*>(&Bs[kk][n0]);
            fma4x4(acc, a0, a1, a2, a3, b4);
        }
        __syncthreads();
    }
    float4 bb = *reinterpret_cast<const float4*>(&bias[h * E_ + n0]);
    float bcol[4] = {bb.x, bb.y, bb.z, bb.w};
    if (VMODE == 0) {
#pragma unroll
        for (int i2 = 0; i2 < 4; ++i2) {
            int m = gm0 + m0 + i2;
            int b = m >> 11, s = m & 2047;
            ushort4 pk;
            pk.x = f2bf(acc[i2][0] + bcol[0]);
            pk.y = f2bf(acc[i2][1] + bcol[1]);
            pk.z = f2bf(acc[i2][2] + bcol[2]);
            pk.w = f2bf(acc[i2][3] + bcol[3]);
            *reinterpret_cast<ushort4*>(
                &out[((size_t)(b * H_ + h) * S_ + s) * E_ + n0]) = pk;
        }
    } else {
        int m = gm0 + m0;
        int b = m >> 11, s = m & 2047;
#pragma unroll
        for (int jj = 0; jj < 4; ++jj) {
            ushort4 pk;
            pk.x = f2bf(acc[0][jj] + bcol[jj]);
            pk.y = f2bf(acc[1][jj] + bcol[jj]);
            pk.z = f2bf(acc[2][jj] + bcol[jj]);
            pk.w = f2bf(acc[3][jj] + bcol[jj]);
            *reinterpret_cast<ushort4*>(
                &out[((size_t)(b * H_ + h) * E_ + n0 + jj) * S_ + s]) = pk;
        }
    }
}

// ---------------------------------------------------------------------------
// Fused attention: QK^T (MFMA bf16) -> two-pass online softmax -> weights
// write (fp32, once) + PV (MFMA bf16) -> attn fp32.
// grid (qt=32, z=32), block 256 (4 waves; each wave owns 16 q-rows).
// ---------------------------------------------------------------------------
__global__ __launch_bounds__(256) void attn_fused_kernel(
    const ushort* __restrict__ qh, const ushort* __restrict__ kh,
    const ushort* __restrict__ vt, float* __restrict__ wts,
    float* __restrict__ attn) {
    const int qt = blockIdx.x, z = blockIdx.y;
    const int q0 = qt * 64;
    const int t = threadIdx.x;
    const int wv = t >> 6;
    const int l = t & 63;
    const int j = l & 15;     // A-row / B-col / D-col lane index
    const int g = l >> 4;     // k-group

    const ushort* qhz = qh + (size_t)z * S_ * E_;
    const ushort* khz = kh + (size_t)z * S_ * E_;
    const ushort* vtz = vt + (size_t)z * E_ * S_;
    float* wz = wts + (size_t)z * S_ * S_;
    float* az = attn + (size_t)z * S_ * E_;

    __shared__ int4 Ks[512];                    // 64 rows x 8 16B-blocks, XOR-swizzled
    __shared__ int4 Vs[512];                    // V^T tile, same swizzle
    __shared__ __align__(16) ushort Ps[4][16][72];  // per-wave P transpose buffer

    // Q fragments (A operand): rows q0 + wv*16 + j, 8 contiguous e per lane
    short8 qf[2];
    {
        const ushort* qrow = qhz + (size_t)(q0 + wv * 16 + j) * E_;
        qf[0] = *reinterpret_cast<const short8*>(qrow + 0 + g * 8);
        qf[1] = *reinterpret_cast<const short8*>(qrow + 32 + g * 8);
    }

    const f32x4 zf = {0.f, 0.f, 0.f, 0.f};
    float m[4], lsum[4];
#pragma unroll
    for (int r = 0; r < 4; ++r) { m[r] = -INFINITY; lsum[r] = 0.f; }

    // ---------------- phase 1: row max + denominator ----------------
    for (int kt = 0; kt <= qt; ++kt) {
        __syncthreads();
        for (int i = t; i < 512; i += 256) {
            int rr = i >> 3, blk = i & 7;
            int4 val = *reinterpret_cast<const int4*>(
                khz + (size_t)(kt * 64 + rr) * E_ + blk * 8);
            Ks[rr * 8 + (blk ^ (rr & 7))] = val;
        }
        __syncthreads();

        f32x4 sacc[4];
#pragma unroll
        for (int n = 0; n < 4; ++n) sacc[n] = zf;
#pragma unroll
        for (int eh = 0; eh < 2; ++eh) {
#pragma unroll
            for (int n = 0; n < 4; ++n) {
                int kc = n * 16 + j;
                int blk = (eh * 4 + g) ^ (kc & 7);
                short8 kf = *reinterpret_cast<const short8*>(&Ks[kc * 8 + blk]);
                sacc[n] = mfma16(qf[eh], kf, sacc[n]);
            }
        }

        float sv[4][4];
#pragma unroll
        for (int n = 0; n < 4; ++n) {
            int cl = n * 16 + j;
#pragma unroll
            for (int r = 0; r < 4; ++r) {
                float vvv = sacc[n][r] * 0.125f;
                int rl = wv * 16 + g * 4 + r;
                if (kt == qt && cl > rl) vvv = -INFINITY;
                sv[n][r] = vvv;
            }
        }
#pragma unroll
        for (int r = 0; r < 4; ++r) {
            float pm = fmaxf(fmaxf(sv[0][r], sv[1][r]), fmaxf(sv[2][r], sv[3][r]));
#pragma unroll
            for (int msk = 1; msk < 16; msk <<= 1)
                pm = fmaxf(pm, __shfl_xor(pm, msk));
            float mn = fmaxf(m[r], pm);
            float s0 = __expf(sv[0][r] - mn) + __expf(sv[1][r] - mn) +
                       __expf(sv[2][r] - mn) + __expf(sv[3][r] - mn);
#pragma unroll
            for (int msk = 1; msk < 16; msk <<= 1)
                s0 += __shfl_xor(s0, msk);
            lsum[r] = lsum[r] * __expf(m[r] - mn) + s0;
            m[r] = mn;
        }
    }

    float invl[4];
#pragma unroll
    for (int r = 0; r < 4; ++r) invl[r] = 1.f / lsum[r];

    f32x4 oacc[4];
#pragma unroll
    for (int n = 0; n < 4; ++n) oacc[n] = zf;

    // ---------------- phase 2: recompute, write weights, PV ----------------
    for (int kt = 0; kt <= qt; ++kt) {
        __syncthreads();
        for (int i = t; i < 512; i += 256) {
            int rr = i >> 3, blk = i & 7;
            int4 kval = *reinterpret_cast<const int4*>(
                khz + (size_t)(kt * 64 + rr) * E_ + blk * 8);
            Ks[rr * 8 + (blk ^ (rr & 7))] = kval;
            int4 vval = *reinterpret_cast<const int4*>(
                vtz + (size_t)rr * S_ + kt * 64 + blk * 8);
            Vs[rr * 8 + (blk ^ (rr & 7))] = vval;
        }
        __syncthreads();

        f32x4 sacc[4];
#pragma unroll
        for (int n = 0; n < 4; ++n) sacc[n] = zf;
#pragma unroll
        for (int eh = 0; eh < 2; ++eh) {
#pragma unroll
            for (int n = 0; n < 4; ++n) {
                int kc = n * 16 + j;
                int blk = (eh * 4 + g) ^ (kc & 7);
                short8 kf = *reinterpret_cast<const short8*>(&Ks[kc * 8 + blk]);
                sacc[n] = mfma16(qf[eh], kf, sacc[n]);
            }
        }

#pragma unroll
        for (int n = 0; n < 4; ++n) {
            int cl = n * 16 + j;
#pragma unroll
            for (int r = 0; r < 4; ++r) {
                float vvv = sacc[n][r] * 0.125f;
                int rl = wv * 16 + g * 4 + r;
                if (kt == qt && cl > rl) vvv = -INFINITY;
                float p = __expf(vvv - m[r]) * invl[r];
                wz[(size_t)(q0 + wv * 16 + g * 4 + r) * S_ + kt * 64 + cl] = p;
                Ps[wv][g * 4 + r][cl] = f2bf(p);
            }
        }

        // PV: A = P[16 q-rows][64 k] from Ps, B = V[64 k][64 e] from Vs
#pragma unroll
        for (int ks = 0; ks < 2; ++ks) {
            short8 pa = *reinterpret_cast<const short8*>(&Ps[wv][j][ks * 32 + g * 8]);
#pragma unroll
            for (int n = 0; n < 4; ++n) {
                int e = n * 16 + j;
                int blk = (ks * 4 + g) ^ (e & 7);
                short8 vb = *reinterpret_cast<const short8*>(&Vs[e * 8 + blk]);
                oacc[n] = mfma16(pa, vb, oacc[n]);
            }
        }
    }

    // write attn (fp32 [z][s][64])
#pragma unroll
    for (int n = 0; n < 4; ++n) {
#pragma unroll
        for (int r = 0; r < 4; ++r) {
            az[(size_t)(q0 + wv * 16 + g * 4 + r) * E_ + n * 16 + j] = oacc[n][r];
        }
    }

    // zero-fill the fully-masked (upper-triangle) weight columns
    int w4 = 16 * (31 - qt);
    if (w4 > 0) {
        float4 z4 = make_float4(0.f, 0.f, 0.f, 0.f);
        for (int row = 0; row < 64; ++row) {
            float4* rp = reinterpret_cast<float4*>(
                wz + (size_t)(q0 + row) * S_ + (qt + 1) * 64);
            for (int c = t; c < w4; c += 256) rp[c] = z4;
        }
    }
}

// ---------------------------------------------------------------------------
// out = concat(attn) @ Wo + bo  (fp32 tiled GEMM).  grid (16, 64), block 256.
// ---------------------------------------------------------------------------
__global__ __launch_bounds__(256) void outproj_kernel(
    const float* __restrict__ attn, const float* __restrict__ Wo,
    const float* __restrict__ bo, float* __restrict__ out) {
    __shared__ float As[64][17];
    __shared__ float Bs[16][68];
    const int t = threadIdx.x;
    const int tx = t & 15, ty = t >> 4;
    const int m0 = ty * 4, n0 = tx * 4;
    const int gn0 = blockIdx.x * 64;
    const int gm0 = blockIdx.y * 64;

    float acc[4][4] = {};
    for (int k0 = 0; k0 < D_; k0 += 16) {
        for (int i = t; i < 64 * 16; i += 256) {
            int m_ = i >> 4, k_ = i & 15;
            int kcol = k0 + k_;
            int h = kcol >> 6, e = kcol & 63;
            int m = gm0 + m_;
            int b = m >> 11, s = m & 2047;
            As[m_][k_] = attn[((size_t)(b * H_ + h) * S_ + s) * E_ + e];
        }
        for (int i = t; i < 16 * 64; i += 256) {
            int k_ = i >> 6, n_ = i & 63;
            Bs[k_][n_] = Wo[(k0 + k_) * D_ + gn0 + n_];
        }
        __syncthreads();
#pragma unroll
        for (int kk = 0; kk < 16; ++kk) {
            float a0 = As[m0 + 0][kk], a1 = As[m0 + 1][kk];
            float a2 = As[m0 + 2][kk], a3 = As[m0 + 3][kk];
            float4 b4 = *reinterpret_cast<const float4*>(&Bs[kk][n0]);
            fma4x4(acc, a0, a1, a2, a3, b4);
        }
        __syncthreads();
    }
    float4 bb = *reinterpret_cast<const float4*>(&bo[gn0 + n0]);
#pragma unroll
    for (int i2 = 0; i2 < 4; ++i2) {
        int m = gm0 + m0 + i2;
        float4 r;
        r.x = acc[i2][0] + bb.x; r.y = acc[i2][1] + bb.y;
        r.z = acc[i2][2] + bb.z; r.w = acc[i2][3] + bb.w;
        *reinterpret_cast<float4*>(&out[(size_t)m * D_ + gn0 + n0]) = r;
    }
}

// ---------------------------------------------------------------------------
extern "C" void kernel_launch(void* const* d_in, const int* in_sizes, int n_in,
                              void* d_out, int out_size, void* d_ws,
                              size_t ws_size, hipStream_t stream) {
    const float* q = (const float*)d_in[0];
    const float* k = (const float*)d_in[1];
    const float* v = (const float*)d_in[2];
    const float* Wq = (const float*)d_in[3];
    const float* bq = (const float*)d_in[4];
    const float* Wk = (const float*)d_in[5];
    const float* bk = (const float*)d_in[6];
    const float* Wv = (const float*)d_in[7];
    const float* bv = (const float*)d_in[8];
    const float* Wo = (const float*)d_in[9];
    const float* bo = (const float*)d_in[10];

    float* out = (float*)d_out;                    // [B,S,D]
    float* wts = out + (size_t)B_ * S_ * D_;       // [B,H,S,S]

    const size_t NZ = (size_t)Z_ * S_ * E_;        // 4,194,304 elems
    ushort* qh = (ushort*)d_ws;                    // bf16 [z][s][64]
    ushort* kh = qh + NZ;                          // bf16 [z][s][64]
    ushort* vt = kh + NZ;                          // bf16 [z][64][s]
    float* attn = (float*)(vt + NZ);               // fp32 [z][s][64]

    dim3 blk(256);
    qkv_proj_bf16_kernel<0><<<dim3(16, 64), blk, 0, stream>>>(q, Wq, bq, qh);
    qkv_proj_bf16_kernel<0><<<dim3(16, 64), blk, 0, stream>>>(k, Wk, bk, kh);
    qkv_proj_bf16_kernel<1><<<dim3(16, 64), blk, 0, stream>>>(v, Wv, bv, vt);
    attn_fused_kernel<<<dim3(32, 32), blk, 0, stream>>>(qh, kh, vt, wts, attn);
    outproj_kernel<<<dim3(16, 64), blk, 0, stream>>>(attn, Wo, bo, out);
}

// Round 3
// 345.873 us; speedup vs baseline: 4.9742x; 3.0513x over previous
//
#include <hip/hip_runtime.h>
#include <math.h>

#define B_ 2
#define S_ 2048
#define D_ 1024
#define H_ 16
#define E_ 64
#define Z_ (B_ * H_)

typedef short short8 __attribute__((ext_vector_type(8)));
typedef float f32x4 __attribute__((ext_vector_type(4)));

__device__ __forceinline__ ushort f2bf(float x) {
    union { float f; unsigned u; } c; c.f = x;
    unsigned r = (c.u + 0x7FFFu + ((c.u >> 16) & 1u)) >> 16;
    return (ushort)r;
}

__device__ __forceinline__ f32x4 mfma16(short8 a, short8 b, f32x4 c) {
    return __builtin_amdgcn_mfma_f32_16x16x32_bf16(a, b, c, 0, 0, 0);
}

// ---------------------------------------------------------------------------
// Weight prep: in fp32 [K][N] (slice blockIdx.z) -> out bf16 [N][K].
// ---------------------------------------------------------------------------
__global__ __launch_bounds__(256) void wtrans_kernel(
    const float* __restrict__ in, ushort* __restrict__ out, int K, int N) {
    __shared__ float tile[32][33];
    const float* ins = in + (size_t)blockIdx.z * K * N;
    ushort* outs = out + (size_t)blockIdx.z * K * N;
    const int k0 = blockIdx.x * 32, n0 = blockIdx.y * 32;
    const int tx = threadIdx.x & 31, ty = threadIdx.x >> 5;  // 32 x 8
#pragma unroll
    for (int r = 0; r < 32; r += 8)
        tile[ty + r][tx] = ins[(size_t)(k0 + ty + r) * N + n0 + tx];
    __syncthreads();
#pragma unroll
    for (int r = 0; r < 32; r += 8)
        outs[(size_t)(n0 + ty + r) * K + k0 + tx] = f2bf(tile[tx][ty + r]);
}

// ---------------------------------------------------------------------------
// MFMA projection: X fp32 [4096][1024] x Wt bf16 [H][64][1024] + bias -> bf16.
// VMODE 0: out[z][s][64]   VMODE 1: out[z][64][s]  (V transposed for attn)
// grid (h=16, mtile=64), block 256 (4 waves; wave owns 16 rows x 64 cols).
// ---------------------------------------------------------------------------
template <int VMODE>
__global__ __launch_bounds__(256) void proj_mfma_kernel(
    const float* __restrict__ X, const ushort* __restrict__ Wt,
    const float* __restrict__ bias, ushort* __restrict__ out) {
    const int h = blockIdx.x;
    const int gm0 = blockIdx.y * 64;
    const int t = threadIdx.x;
    const int wv = t >> 6, l = t & 63, j = l & 15, g = l >> 4;

    __shared__ int4 Xs[512];   // 64 m-rows x 8 16B-blocks (64 k), XOR-swizzled
    __shared__ int4 Wsh[512];  // 64 e-rows x 8 16B-blocks (64 k), XOR-swizzled
    const ushort* Wh = Wt + (size_t)h * E_ * D_;

    const f32x4 zf = {0.f, 0.f, 0.f, 0.f};
    f32x4 acc[4];
#pragma unroll
    for (int n = 0; n < 4; ++n) acc[n] = zf;

    for (int k0 = 0; k0 < D_; k0 += 64) {
        __syncthreads();
        for (int i = t; i < 512; i += 256) {
            int rr = i >> 3, blk = i & 7;
            const float* xp = X + (size_t)(gm0 + rr) * D_ + k0 + blk * 8;
            float4 x0 = *reinterpret_cast<const float4*>(xp);
            float4 x1 = *reinterpret_cast<const float4*>(xp + 4);
            union { int4 v; ushort u[8]; } pk;
            pk.u[0] = f2bf(x0.x); pk.u[1] = f2bf(x0.y);
            pk.u[2] = f2bf(x0.z); pk.u[3] = f2bf(x0.w);
            pk.u[4] = f2bf(x1.x); pk.u[5] = f2bf(x1.y);
            pk.u[6] = f2bf(x1.z); pk.u[7] = f2bf(x1.w);
            Xs[rr * 8 + (blk ^ (rr & 7))] = pk.v;
            Wsh[rr * 8 + (blk ^ (rr & 7))] = *reinterpret_cast<const int4*>(
                Wh + (size_t)rr * D_ + k0 + blk * 8);
        }
        __syncthreads();
        const int arow = wv * 16 + j;
#pragma unroll
        for (int eh = 0; eh < 2; ++eh) {
            short8 a = *reinterpret_cast<const short8*>(
                &Xs[arow * 8 + ((eh * 4 + g) ^ (arow & 7))]);
#pragma unroll
            for (int n = 0; n < 4; ++n) {
                int e = n * 16 + j;
                short8 b = *reinterpret_cast<const short8*>(
                    &Wsh[e * 8 + ((eh * 4 + g) ^ (e & 7))]);
                acc[n] = mfma16(a, b, acc[n]);
            }
        }
    }

#pragma unroll
    for (int n = 0; n < 4; ++n) {
        const int col = n * 16 + j;
        const float bv = bias[h * E_ + col];
#pragma unroll
        for (int r = 0; r < 4; ++r) {
            int m = gm0 + wv * 16 + g * 4 + r;
            int b = m >> 11, s = m & 2047;
            ushort val = f2bf(acc[n][r] + bv);
            if (VMODE == 0)
                out[((size_t)(b * H_ + h) * S_ + s) * E_ + col] = val;
            else
                out[((size_t)(b * H_ + h) * E_ + col) * S_ + s] = val;
        }
    }
}

// ---------------------------------------------------------------------------
// Fused attention: QK^T (MFMA bf16) -> two-pass online softmax -> weights
// write (fp32, once) + PV (MFMA bf16) -> attn bf16 in concat layout
// [b][s][h*64+e].   grid (qt=32, z=32), block 256.
// ---------------------------------------------------------------------------
__global__ __launch_bounds__(256) void attn_fused_kernel(
    const ushort* __restrict__ qh, const ushort* __restrict__ kh,
    const ushort* __restrict__ vt, float* __restrict__ wts,
    ushort* __restrict__ attnc) {
    const int qt = blockIdx.x, z = blockIdx.y;
    const int q0 = qt * 64;
    const int t = threadIdx.x;
    const int wv = t >> 6;
    const int l = t & 63;
    const int j = l & 15;
    const int g = l >> 4;

    const ushort* qhz = qh + (size_t)z * S_ * E_;
    const ushort* khz = kh + (size_t)z * S_ * E_;
    const ushort* vtz = vt + (size_t)z * E_ * S_;
    float* wz = wts + (size_t)z * S_ * S_;

    __shared__ int4 Ks[512];
    __shared__ int4 Vs[512];
    __shared__ __align__(16) ushort Ps[4][16][72];

    short8 qf[2];
    {
        const ushort* qrow = qhz + (size_t)(q0 + wv * 16 + j) * E_;
        qf[0] = *reinterpret_cast<const short8*>(qrow + 0 + g * 8);
        qf[1] = *reinterpret_cast<const short8*>(qrow + 32 + g * 8);
    }

    const f32x4 zf = {0.f, 0.f, 0.f, 0.f};
    float m[4], lsum[4];
#pragma unroll
    for (int r = 0; r < 4; ++r) { m[r] = -INFINITY; lsum[r] = 0.f; }

    // ---------------- phase 1: row max + denominator ----------------
    for (int kt = 0; kt <= qt; ++kt) {
        __syncthreads();
        for (int i = t; i < 512; i += 256) {
            int rr = i >> 3, blk = i & 7;
            int4 val = *reinterpret_cast<const int4*>(
                khz + (size_t)(kt * 64 + rr) * E_ + blk * 8);
            Ks[rr * 8 + (blk ^ (rr & 7))] = val;
        }
        __syncthreads();

        f32x4 sacc[4];
#pragma unroll
        for (int n = 0; n < 4; ++n) sacc[n] = zf;
#pragma unroll
        for (int eh = 0; eh < 2; ++eh) {
#pragma unroll
            for (int n = 0; n < 4; ++n) {
                int kc = n * 16 + j;
                int blk = (eh * 4 + g) ^ (kc & 7);
                short8 kf = *reinterpret_cast<const short8*>(&Ks[kc * 8 + blk]);
                sacc[n] = mfma16(qf[eh], kf, sacc[n]);
            }
        }

        float sv[4][4];
#pragma unroll
        for (int n = 0; n < 4; ++n) {
            int cl = n * 16 + j;
#pragma unroll
            for (int r = 0; r < 4; ++r) {
                float vvv = sacc[n][r] * 0.125f;
                int rl = wv * 16 + g * 4 + r;
                if (kt == qt && cl > rl) vvv = -INFINITY;
                sv[n][r] = vvv;
            }
        }
#pragma unroll
        for (int r = 0; r < 4; ++r) {
            float pm = fmaxf(fmaxf(sv[0][r], sv[1][r]), fmaxf(sv[2][r], sv[3][r]));
#pragma unroll
            for (int msk = 1; msk < 16; msk <<= 1)
                pm = fmaxf(pm, __shfl_xor(pm, msk));
            float mn = fmaxf(m[r], pm);
            float s0 = __expf(sv[0][r] - mn) + __expf(sv[1][r] - mn) +
                       __expf(sv[2][r] - mn) + __expf(sv[3][r] - mn);
#pragma unroll
            for (int msk = 1; msk < 16; msk <<= 1)
                s0 += __shfl_xor(s0, msk);
            lsum[r] = lsum[r] * __expf(m[r] - mn) + s0;
            m[r] = mn;
        }
    }

    float invl[4];
#pragma unroll
    for (int r = 0; r < 4; ++r) invl[r] = 1.f / lsum[r];

    f32x4 oacc[4];
#pragma unroll
    for (int n = 0; n < 4; ++n) oacc[n] = zf;

    // ---------------- phase 2: recompute, write weights, PV ----------------
    for (int kt = 0; kt <= qt; ++kt) {
        __syncthreads();
        for (int i = t; i < 512; i += 256) {
            int rr = i >> 3, blk = i & 7;
            int4 kval = *reinterpret_cast<const int4*>(
                khz + (size_t)(kt * 64 + rr) * E_ + blk * 8);
            Ks[rr * 8 + (blk ^ (rr & 7))] = kval;
            int4 vval = *reinterpret_cast<const int4*>(
                vtz + (size_t)rr * S_ + kt * 64 + blk * 8);
            Vs[rr * 8 + (blk ^ (rr & 7))] = vval;
        }
        __syncthreads();

        f32x4 sacc[4];
#pragma unroll
        for (int n = 0; n < 4; ++n) sacc[n] = zf;
#pragma unroll
        for (int eh = 0; eh < 2; ++eh) {
#pragma unroll
            for (int n = 0; n < 4; ++n) {
                int kc = n * 16 + j;
                int blk = (eh * 4 + g) ^ (kc & 7);
                short8 kf = *reinterpret_cast<const short8*>(&Ks[kc * 8 + blk]);
                sacc[n] = mfma16(qf[eh], kf, sacc[n]);
            }
        }

#pragma unroll
        for (int n = 0; n < 4; ++n) {
            int cl = n * 16 + j;
#pragma unroll
            for (int r = 0; r < 4; ++r) {
                float vvv = sacc[n][r] * 0.125f;
                int rl = wv * 16 + g * 4 + r;
                if (kt == qt && cl > rl) vvv = -INFINITY;
                float p = __expf(vvv - m[r]) * invl[r];
                wz[(size_t)(q0 + wv * 16 + g * 4 + r) * S_ + kt * 64 + cl] = p;
                Ps[wv][g * 4 + r][cl] = f2bf(p);
            }
        }

#pragma unroll
        for (int ks = 0; ks < 2; ++ks) {
            short8 pa = *reinterpret_cast<const short8*>(&Ps[wv][j][ks * 32 + g * 8]);
#pragma unroll
            for (int n = 0; n < 4; ++n) {
                int e = n * 16 + j;
                int blk = (ks * 4 + g) ^ (e & 7);
                short8 vb = *reinterpret_cast<const short8*>(&Vs[e * 8 + blk]);
                oacc[n] = mfma16(pa, vb, oacc[n]);
            }
        }
    }

    // write attn bf16 in concat layout [b][s][h*64+e]
    {
        const int b = z >> 4, hh = z & 15;
#pragma unroll
        for (int n = 0; n < 4; ++n) {
#pragma unroll
            for (int r = 0; r < 4; ++r) {
                int s = q0 + wv * 16 + g * 4 + r;
                attnc[((size_t)(b * S_ + s)) * D_ + hh * E_ + n * 16 + j] =
                    f2bf(oacc[n][r]);
            }
        }
    }

    // zero-fill the fully-masked (upper-triangle) weight columns
    int w4 = 16 * (31 - qt);
    if (w4 > 0) {
        float4 z4 = make_float4(0.f, 0.f, 0.f, 0.f);
        for (int row = 0; row < 64; ++row) {
            float4* rp = reinterpret_cast<float4*>(
                wz + (size_t)(q0 + row) * S_ + (qt + 1) * 64);
            for (int c = t; c < w4; c += 256) rp[c] = z4;
        }
    }
}

// ---------------------------------------------------------------------------
// MFMA out-projection: A bf16 [4096][1024] x Wot bf16 [1024][1024] ([n][k])
// + bo -> out fp32 [4096][1024].  grid (ntile=16, mtile=64), block 256.
// ---------------------------------------------------------------------------
__global__ __launch_bounds__(256) void outproj_mfma_kernel(
    const ushort* __restrict__ A, const ushort* __restrict__ Wot,
    const float* __restrict__ bo, float* __restrict__ out) {
    const int gn0 = blockIdx.x * 64;
    const int gm0 = blockIdx.y * 64;
    const int t = threadIdx.x;
    const int wv = t >> 6, l = t & 63, j = l & 15, g = l >> 4;

    __shared__ int4 As[512];
    __shared__ int4 Bs[512];

    const f32x4 zf = {0.f, 0.f, 0.f, 0.f};
    f32x4 acc[4];
#pragma unroll
    for (int n = 0; n < 4; ++n) acc[n] = zf;

    for (int k0 = 0; k0 < D_; k0 += 64) {
        __syncthreads();
        for (int i = t; i < 512; i += 256) {
            int rr = i >> 3, blk = i & 7;
            As[rr * 8 + (blk ^ (rr & 7))] = *reinterpret_cast<const int4*>(
                A + (size_t)(gm0 + rr) * D_ + k0 + blk * 8);
            Bs[rr * 8 + (blk ^ (rr & 7))] = *reinterpret_cast<const int4*>(
                Wot + (size_t)(gn0 + rr) * D_ + k0 + blk * 8);
        }
        __syncthreads();
        const int arow = wv * 16 + j;
#pragma unroll
        for (int eh = 0; eh < 2; ++eh) {
            short8 a = *reinterpret_cast<const short8*>(
                &As[arow * 8 + ((eh * 4 + g) ^ (arow & 7))]);
#pragma unroll
            for (int n = 0; n < 4; ++n) {
                int e = n * 16 + j;
                short8 b = *reinterpret_cast<const short8*>(
                    &Bs[e * 8 + ((eh * 4 + g) ^ (e & 7))]);
                acc[n] = mfma16(a, b, acc[n]);
            }
        }
    }

#pragma unroll
    for (int n = 0; n < 4; ++n) {
        const int col = gn0 + n * 16 + j;
        const float bv = bo[col];
#pragma unroll
        for (int r = 0; r < 4; ++r) {
            int m = gm0 + wv * 16 + g * 4 + r;
            out[(size_t)m * D_ + col] = acc[n][r] + bv;
        }
    }
}

// ---------------------------------------------------------------------------
extern "C" void kernel_launch(void* const* d_in, const int* in_sizes, int n_in,
                              void* d_out, int out_size, void* d_ws,
                              size_t ws_size, hipStream_t stream) {
    const float* q = (const float*)d_in[0];
    const float* k = (const float*)d_in[1];
    const float* v = (const float*)d_in[2];
    const float* Wq = (const float*)d_in[3];
    const float* bq = (const float*)d_in[4];
    const float* Wk = (const float*)d_in[5];
    const float* bk = (const float*)d_in[6];
    const float* Wv = (const float*)d_in[7];
    const float* bv = (const float*)d_in[8];
    const float* Wo = (const float*)d_in[9];
    const float* bo = (const float*)d_in[10];

    float* out = (float*)d_out;                    // [B,S,D]
    float* wts = out + (size_t)B_ * S_ * D_;       // [B,H,S,S]

    const size_t NZ = (size_t)Z_ * S_ * E_;        // 4,194,304
    const size_t NW = (size_t)H_ * E_ * D_;        // 1,048,576
    ushort* qh = (ushort*)d_ws;                    // bf16 [z][s][64]
    ushort* kh = qh + NZ;                          // bf16 [z][s][64]
    ushort* vt = kh + NZ;                          // bf16 [z][64][s]
    ushort* attnc = vt + NZ;                       // bf16 [4096][1024] concat
    ushort* Wqt = attnc + NZ;                      // bf16 [h][64][1024]
    ushort* Wkt = Wqt + NW;
    ushort* Wvt = Wkt + NW;
    ushort* Wot = Wvt + NW;                        // bf16 [1024][1024] ([n][k])

    dim3 blk(256);
    wtrans_kernel<<<dim3(32, 2, 16), blk, 0, stream>>>(Wq, Wqt, D_, E_);
    wtrans_kernel<<<dim3(32, 2, 16), blk, 0, stream>>>(Wk, Wkt, D_, E_);
    wtrans_kernel<<<dim3(32, 2, 16), blk, 0, stream>>>(Wv, Wvt, D_, E_);
    wtrans_kernel<<<dim3(32, 32, 1), blk, 0, stream>>>(Wo, Wot, D_, D_);
    proj_mfma_kernel<0><<<dim3(16, 64), blk, 0, stream>>>(q, Wqt, bq, qh);
    proj_mfma_kernel<0><<<dim3(16, 64), blk, 0, stream>>>(k, Wkt, bk, kh);
    proj_mfma_kernel<1><<<dim3(16, 64), blk, 0, stream>>>(v, Wvt, bv, vt);
    attn_fused_kernel<<<dim3(32, 32), blk, 0, stream>>>(qh, kh, vt, wts, attnc);
    outproj_mfma_kernel<<<dim3(16, 64), blk, 0, stream>>>(attnc, Wot, bo, out);
}

// Round 4
// 299.020 us; speedup vs baseline: 5.7536x; 1.1567x over previous
//
#include <hip/hip_runtime.h>
#include <math.h>

#define B_ 2
#define S_ 2048
#define D_ 1024
#define H_ 16
#define E_ 64
#define Z_ (B_ * H_)
#define QBLK 128
#define NEG_BIG (-1e30f)

typedef short short8 __attribute__((ext_vector_type(8)));
typedef float f32x4 __attribute__((ext_vector_type(4)));

__device__ __forceinline__ ushort f2bf(float x) {
    union { float f; unsigned u; } c; c.f = x;
    unsigned r = (c.u + 0x7FFFu + ((c.u >> 16) & 1u)) >> 16;
    return (ushort)r;
}

__device__ __forceinline__ f32x4 mfma16(short8 a, short8 b, f32x4 c) {
    return __builtin_amdgcn_mfma_f32_16x16x32_bf16(a, b, c, 0, 0, 0);
}

// ---------------------------------------------------------------------------
// Weight prep: in fp32 [K][N] (slice blockIdx.z) -> out bf16 [N][K].
// ---------------------------------------------------------------------------
__global__ __launch_bounds__(256) void wtrans_kernel(
    const float* __restrict__ in, ushort* __restrict__ out, int K, int N) {
    __shared__ float tile[32][33];
    const float* ins = in + (size_t)blockIdx.z * K * N;
    ushort* outs = out + (size_t)blockIdx.z * K * N;
    const int k0 = blockIdx.x * 32, n0 = blockIdx.y * 32;
    const int tx = threadIdx.x & 31, ty = threadIdx.x >> 5;  // 32 x 8
#pragma unroll
    for (int r = 0; r < 32; r += 8)
        tile[ty + r][tx] = ins[(size_t)(k0 + ty + r) * N + n0 + tx];
    __syncthreads();
#pragma unroll
    for (int r = 0; r < 32; r += 8)
        outs[(size_t)(n0 + ty + r) * K + k0 + tx] = f2bf(tile[tx][ty + r]);
}

// ---------------------------------------------------------------------------
// MFMA projection: X fp32 [4096][1024] x Wt bf16 [H][64][1024] + bias -> bf16.
// VMODE 0: out[z][s][64]   VMODE 1: out[z][64][s]  (V transposed for attn)
// 1-D grid 1024 blocks (XCD-swizzled: 8 m-subtiles x 16 heads per XCD).
// oscale: multiplied into (acc+bias); used to fold 0.125*log2e into Q.
// ---------------------------------------------------------------------------
template <int VMODE>
__global__ __launch_bounds__(256) void proj_mfma_kernel(
    const float* __restrict__ X, const ushort* __restrict__ Wt,
    const float* __restrict__ bias, ushort* __restrict__ out, float oscale) {
    const int f = blockIdx.x;
    const int xcd = f & 7, w = f >> 3;
    const int h = w >> 3;
    const int gm0 = (xcd * 8 + (w & 7)) * 64;
    const int t = threadIdx.x;
    const int wv = t >> 6, l = t & 63, j = l & 15, g = l >> 4;

    __shared__ int4 Xs[512];   // 64 m-rows x 8 16B-blocks (64 k), XOR-swizzled
    __shared__ int4 Wsh[512];  // 64 e-rows x 8 16B-blocks (64 k), XOR-swizzled
    const ushort* Wh = Wt + (size_t)h * E_ * D_;

    const f32x4 zf = {0.f, 0.f, 0.f, 0.f};
    f32x4 acc[4];
#pragma unroll
    for (int n = 0; n < 4; ++n) acc[n] = zf;

    for (int k0 = 0; k0 < D_; k0 += 64) {
        __syncthreads();
        for (int i = t; i < 512; i += 256) {
            int rr = i >> 3, blk = i & 7;
            const float* xp = X + (size_t)(gm0 + rr) * D_ + k0 + blk * 8;
            float4 x0 = *reinterpret_cast<const float4*>(xp);
            float4 x1 = *reinterpret_cast<const float4*>(xp + 4);
            union { int4 v; ushort u[8]; } pk;
            pk.u[0] = f2bf(x0.x); pk.u[1] = f2bf(x0.y);
            pk.u[2] = f2bf(x0.z); pk.u[3] = f2bf(x0.w);
            pk.u[4] = f2bf(x1.x); pk.u[5] = f2bf(x1.y);
            pk.u[6] = f2bf(x1.z); pk.u[7] = f2bf(x1.w);
            Xs[rr * 8 + (blk ^ (rr & 7))] = pk.v;
            Wsh[rr * 8 + (blk ^ (rr & 7))] = *reinterpret_cast<const int4*>(
                Wh + (size_t)rr * D_ + k0 + blk * 8);
        }
        __syncthreads();
        const int arow = wv * 16 + j;
        __builtin_amdgcn_s_setprio(1);
#pragma unroll
        for (int eh = 0; eh < 2; ++eh) {
            short8 a = *reinterpret_cast<const short8*>(
                &Xs[arow * 8 + ((eh * 4 + g) ^ (arow & 7))]);
#pragma unroll
            for (int n = 0; n < 4; ++n) {
                int e = n * 16 + j;
                short8 b = *reinterpret_cast<const short8*>(
                    &Wsh[e * 8 + ((eh * 4 + g) ^ (e & 7))]);
                acc[n] = mfma16(a, b, acc[n]);
            }
        }
        __builtin_amdgcn_s_setprio(0);
    }

#pragma unroll
    for (int n = 0; n < 4; ++n) {
        const int col = n * 16 + j;
        const float bv = bias[h * E_ + col];
#pragma unroll
        for (int r = 0; r < 4; ++r) {
            int m = gm0 + wv * 16 + g * 4 + r;
            int b = m >> 11, s = m & 2047;
            ushort val = f2bf((acc[n][r] + bv) * oscale);
            if (VMODE == 0)
                out[((size_t)(b * H_ + h) * S_ + s) * E_ + col] = val;
            else
                out[((size_t)(b * H_ + h) * E_ + col) * S_ + s] = val;
        }
    }
}

// ---------------------------------------------------------------------------
// Fused attention, QBLK=128, 8 waves, two-pass online softmax with per-lane
// phase-1 state (no per-tile shuffles), double-buffered K/V staging, XCD
// swizzle.  Scores arrive pre-scaled to the exp2 domain (Q folded).
// grid 512 blocks x 512 threads.
// ---------------------------------------------------------------------------
__global__ __launch_bounds__(512) void attn_fused_kernel(
    const ushort* __restrict__ qh, const ushort* __restrict__ kh,
    const ushort* __restrict__ vt, float* __restrict__ wts,
    ushort* __restrict__ attnc) {
    const int f = blockIdx.x;
    const int xcd = f & 7, w = f >> 3;
    const int z = xcd * 4 + (w >> 4);
    const int qt = w & 15;
    const int q0 = qt * QBLK;
    const int ktmax = 2 * qt + 1;

    const int t = threadIdx.x;
    const int wv = t >> 6, l = t & 63, j = l & 15, g = l >> 4;

    const ushort* qhz = qh + (size_t)z * S_ * E_;
    const ushort* khz = kh + (size_t)z * S_ * E_;
    const ushort* vtz = vt + (size_t)z * E_ * S_;
    float* wz = wts + (size_t)z * S_ * S_;

    __shared__ int4 Kb[2][512];
    __shared__ int4 Vb[2][512];
    __shared__ __align__(16) ushort Ps[8][16][72];

    const int rr = t >> 3, bb = t & 7;
    const int lds_i = rr * 8 + (bb ^ (rr & 7));
    const int koff = rr * 64 + bb * 8;     // elems into K z-slice (+ kt*4096)
    const int voff = rr * 2048 + bb * 8;   // elems into V^T z-slice (+ kt*64)

    short8 qf[2];
    {
        const ushort* qrow = qhz + (size_t)(q0 + wv * 16 + j) * E_;
        qf[0] = *reinterpret_cast<const short8*>(qrow + g * 8);
        qf[1] = *reinterpret_cast<const short8*>(qrow + 32 + g * 8);
    }
    const int qr_base = q0 + wv * 16 + g * 4;  // + r

    const f32x4 zf = {0.f, 0.f, 0.f, 0.f};
    float m[4], lsum[4];
#pragma unroll
    for (int r = 0; r < 4; ++r) { m[r] = NEG_BIG; lsum[r] = 0.f; }

    // ---------------- phase 1: per-lane online max+denominator ----------
    Kb[0][lds_i] = *reinterpret_cast<const int4*>(khz + koff);
    __syncthreads();
    for (int kt = 0; kt <= ktmax; ++kt) {
        const int cur = kt & 1;
        const bool pf = (kt < ktmax);
        int4 kreg;
        if (pf)
            kreg = *reinterpret_cast<const int4*>(khz + (kt + 1) * 4096 + koff);

        f32x4 sacc[4];
#pragma unroll
        for (int n = 0; n < 4; ++n) sacc[n] = zf;
        __builtin_amdgcn_s_setprio(1);
#pragma unroll
        for (int eh = 0; eh < 2; ++eh) {
#pragma unroll
            for (int n = 0; n < 4; ++n) {
                const int kc = n * 16 + j;
                short8 kf = *reinterpret_cast<const short8*>(
                    &Kb[cur][kc * 8 + ((eh * 4 + g) ^ (j & 7))]);
                sacc[n] = mfma16(qf[eh], kf, sacc[n]);
            }
        }
        __builtin_amdgcn_s_setprio(0);

        float sv[4][4];
#pragma unroll
        for (int n = 0; n < 4; ++n)
#pragma unroll
            for (int r = 0; r < 4; ++r) sv[n][r] = sacc[n][r];
        if (kt >= 2 * qt) {
#pragma unroll
            for (int n = 0; n < 4; ++n) {
                const int col = kt * 64 + n * 16 + j;
#pragma unroll
                for (int r = 0; r < 4; ++r)
                    if (col > qr_base + r) sv[n][r] = NEG_BIG;
            }
        }
#pragma unroll
        for (int r = 0; r < 4; ++r) {
            float mn = fmaxf(fmaxf(m[r], fmaxf(sv[0][r], sv[1][r])),
                             fmaxf(sv[2][r], sv[3][r]));
            float resc = exp2f(m[r] - mn);
            lsum[r] = lsum[r] * resc +
                      (exp2f(sv[0][r] - mn) + exp2f(sv[1][r] - mn)) +
                      (exp2f(sv[2][r] - mn) + exp2f(sv[3][r] - mn));
            m[r] = mn;
        }

        if (pf) Kb[cur ^ 1][lds_i] = kreg;
        __syncthreads();
    }

    // one-time cross-lane merge (16 lanes j share a q-row)
    float mrow[4], invl[4];
#pragma unroll
    for (int r = 0; r < 4; ++r) {
        float mr = m[r];
        mr = fmaxf(mr, __shfl_xor(mr, 1));
        mr = fmaxf(mr, __shfl_xor(mr, 2));
        mr = fmaxf(mr, __shfl_xor(mr, 4));
        mr = fmaxf(mr, __shfl_xor(mr, 8));
        float tt = lsum[r] * exp2f(m[r] - mr);
        tt += __shfl_xor(tt, 1);
        tt += __shfl_xor(tt, 2);
        tt += __shfl_xor(tt, 4);
        tt += __shfl_xor(tt, 8);
        mrow[r] = mr;
        invl[r] = 1.0f / tt;
    }

    // ---------------- phase 2: recompute, write weights, PV -------------
    f32x4 oacc[4];
#pragma unroll
    for (int n = 0; n < 4; ++n) oacc[n] = zf;

    Kb[0][lds_i] = *reinterpret_cast<const int4*>(khz + koff);
    Vb[0][lds_i] = *reinterpret_cast<const int4*>(vtz + voff);
    __syncthreads();
    for (int kt = 0; kt <= ktmax; ++kt) {
        const int cur = kt & 1;
        const bool pf = (kt < ktmax);
        int4 kreg, vreg;
        if (pf) {
            kreg = *reinterpret_cast<const int4*>(khz + (kt + 1) * 4096 + koff);
            vreg = *reinterpret_cast<const int4*>(vtz + (kt + 1) * 64 + voff);
        }

        f32x4 sacc[4];
#pragma unroll
        for (int n = 0; n < 4; ++n) sacc[n] = zf;
        __builtin_amdgcn_s_setprio(1);
#pragma unroll
        for (int eh = 0; eh < 2; ++eh) {
#pragma unroll
            for (int n = 0; n < 4; ++n) {
                const int kc = n * 16 + j;
                short8 kf = *reinterpret_cast<const short8*>(
                    &Kb[cur][kc * 8 + ((eh * 4 + g) ^ (j & 7))]);
                sacc[n] = mfma16(qf[eh], kf, sacc[n]);
            }
        }
        __builtin_amdgcn_s_setprio(0);

        float sv[4][4];
#pragma unroll
        for (int n = 0; n < 4; ++n)
#pragma unroll
            for (int r = 0; r < 4; ++r) sv[n][r] = sacc[n][r];
        if (kt >= 2 * qt) {
#pragma unroll
            for (int n = 0; n < 4; ++n) {
                const int col = kt * 64 + n * 16 + j;
#pragma unroll
                for (int r = 0; r < 4; ++r)
                    if (col > qr_base + r) sv[n][r] = NEG_BIG;
            }
        }

#pragma unroll
        for (int n = 0; n < 4; ++n) {
#pragma unroll
            for (int r = 0; r < 4; ++r) {
                float p = exp2f(sv[n][r] - mrow[r]) * invl[r];
                wz[(size_t)(qr_base + r) * S_ + kt * 64 + n * 16 + j] = p;
                Ps[wv][g * 4 + r][n * 16 + j] = f2bf(p);
            }
        }

        __builtin_amdgcn_s_setprio(1);
#pragma unroll
        for (int ks = 0; ks < 2; ++ks) {
            short8 pa =
                *reinterpret_cast<const short8*>(&Ps[wv][j][ks * 32 + g * 8]);
#pragma unroll
            for (int n = 0; n < 4; ++n) {
                const int e = n * 16 + j;
                short8 vb = *reinterpret_cast<const short8*>(
                    &Vb[cur][e * 8 + ((ks * 4 + g) ^ (j & 7))]);
                oacc[n] = mfma16(pa, vb, oacc[n]);
            }
        }
        __builtin_amdgcn_s_setprio(0);

        if (pf) {
            Kb[cur ^ 1][lds_i] = kreg;
            Vb[cur ^ 1][lds_i] = vreg;
        }
        __syncthreads();
    }

    // write attn bf16 in concat layout [b][s][h*64+e]
    {
        const int b = z >> 4, hh = z & 15;
#pragma unroll
        for (int n = 0; n < 4; ++n)
#pragma unroll
            for (int r = 0; r < 4; ++r)
                attnc[((size_t)(b * S_ + qr_base + r)) * D_ + hh * E_ +
                      n * 16 + j] = f2bf(oacc[n][r]);
    }

    // zero-fill the fully-masked (upper-triangle) weight columns
    const int c0 = q0 + QBLK;
    const int w4 = (S_ - c0) >> 2;
    if (w4 > 0) {
        const float4 z4 = make_float4(0.f, 0.f, 0.f, 0.f);
        for (int row = 0; row < QBLK; ++row) {
            float4* rp =
                reinterpret_cast<float4*>(wz + (size_t)(q0 + row) * S_ + c0);
            for (int c = t; c < w4; c += 512) rp[c] = z4;
        }
    }
}

// ---------------------------------------------------------------------------
// MFMA out-projection: A bf16 [4096][1024] x Wot bf16 [1024][1024] ([n][k])
// + bo -> out fp32.  1-D grid 1024 blocks (XCD-swizzled).
// ---------------------------------------------------------------------------
__global__ __launch_bounds__(256) void outproj_mfma_kernel(
    const ushort* __restrict__ A, const ushort* __restrict__ Wot,
    const float* __restrict__ bo, float* __restrict__ out) {
    const int f = blockIdx.x;
    const int xcd = f & 7, w = f >> 3;
    const int gm0 = (xcd * 8 + (w & 7)) * 64;
    const int gn0 = (w >> 3) * 64;
    const int t = threadIdx.x;
    const int wv = t >> 6, l = t & 63, j = l & 15, g = l >> 4;

    __shared__ int4 As[512];
    __shared__ int4 Bs[512];

    const f32x4 zf = {0.f, 0.f, 0.f, 0.f};
    f32x4 acc[4];
#pragma unroll
    for (int n = 0; n < 4; ++n) acc[n] = zf;

    for (int k0 = 0; k0 < D_; k0 += 64) {
        __syncthreads();
        for (int i = t; i < 512; i += 256) {
            int rr = i >> 3, blk = i & 7;
            As[rr * 8 + (blk ^ (rr & 7))] = *reinterpret_cast<const int4*>(
                A + (size_t)(gm0 + rr) * D_ + k0 + blk * 8);
            Bs[rr * 8 + (blk ^ (rr & 7))] = *reinterpret_cast<const int4*>(
                Wot + (size_t)(gn0 + rr) * D_ + k0 + blk * 8);
        }
        __syncthreads();
        const int arow = wv * 16 + j;
        __builtin_amdgcn_s_setprio(1);
#pragma unroll
        for (int eh = 0; eh < 2; ++eh) {
            short8 a = *reinterpret_cast<const short8*>(
                &As[arow * 8 + ((eh * 4 + g) ^ (arow & 7))]);
#pragma unroll
            for (int n = 0; n < 4; ++n) {
                int e = n * 16 + j;
                short8 b = *reinterpret_cast<const short8*>(
                    &Bs[e * 8 + ((eh * 4 + g) ^ (e & 7))]);
                acc[n] = mfma16(a, b, acc[n]);
            }
        }
        __builtin_amdgcn_s_setprio(0);
    }

#pragma unroll
    for (int n = 0; n < 4; ++n) {
        const int col = gn0 + n * 16 + j;
        const float bv = bo[col];
#pragma unroll
        for (int r = 0; r < 4; ++r) {
            int mm = gm0 + wv * 16 + g * 4 + r;
            out[(size_t)mm * D_ + col] = acc[n][r] + bv;
        }
    }
}

// ---------------------------------------------------------------------------
extern "C" void kernel_launch(void* const* d_in, const int* in_sizes, int n_in,
                              void* d_out, int out_size, void* d_ws,
                              size_t ws_size, hipStream_t stream) {
    const float* q = (const float*)d_in[0];
    const float* k = (const float*)d_in[1];
    const float* v = (const float*)d_in[2];
    const float* Wq = (const float*)d_in[3];
    const float* bq = (const float*)d_in[4];
    const float* Wk = (const float*)d_in[5];
    const float* bk = (const float*)d_in[6];
    const float* Wv = (const float*)d_in[7];
    const float* bv = (const float*)d_in[8];
    const float* Wo = (const float*)d_in[9];
    const float* bo = (const float*)d_in[10];

    float* out = (float*)d_out;                    // [B,S,D]
    float* wts = out + (size_t)B_ * S_ * D_;       // [B,H,S,S]

    const size_t NZ = (size_t)Z_ * S_ * E_;        // 4,194,304
    const size_t NW = (size_t)H_ * E_ * D_;        // 1,048,576
    ushort* qh = (ushort*)d_ws;                    // bf16 [z][s][64] (scaled)
    ushort* kh = qh + NZ;                          // bf16 [z][s][64]
    ushort* vt = kh + NZ;                          // bf16 [z][64][s]
    ushort* attnc = vt + NZ;                       // bf16 [4096][1024] concat
    ushort* Wqt = attnc + NZ;                      // bf16 [h][64][1024]
    ushort* Wkt = Wqt + NW;
    ushort* Wvt = Wkt + NW;
    ushort* Wot = Wvt + NW;                        // bf16 [1024][1024] ([n][k])

    const float QSCALE = 0.125f * 1.44269504088896340736f;  // 1/8 * log2(e)

    dim3 blk(256);
    wtrans_kernel<<<dim3(32, 2, 16), blk, 0, stream>>>(Wq, Wqt, D_, E_);
    wtrans_kernel<<<dim3(32, 2, 16), blk, 0, stream>>>(Wk, Wkt, D_, E_);
    wtrans_kernel<<<dim3(32, 2, 16), blk, 0, stream>>>(Wv, Wvt, D_, E_);
    wtrans_kernel<<<dim3(32, 32, 1), blk, 0, stream>>>(Wo, Wot, D_, D_);
    proj_mfma_kernel<0><<<dim3(1024), blk, 0, stream>>>(q, Wqt, bq, qh, QSCALE);
    proj_mfma_kernel<0><<<dim3(1024), blk, 0, stream>>>(k, Wkt, bk, kh, 1.0f);
    proj_mfma_kernel<1><<<dim3(1024), blk, 0, stream>>>(v, Wvt, bv, vt, 1.0f);
    attn_fused_kernel<<<dim3(512), dim3(512), 0, stream>>>(qh, kh, vt, wts,
                                                           attnc);
    outproj_mfma_kernel<<<dim3(1024), blk, 0, stream>>>(attnc, Wot, bo, out);
}

// Round 5
// 257.641 us; speedup vs baseline: 6.6776x; 1.1606x over previous
//
#include <hip/hip_runtime.h>
#include <math.h>

#define B_ 2
#define S_ 2048
#define D_ 1024
#define H_ 16
#define E_ 64
#define Z_ (B_ * H_)
#define QBLK 128
#define NEG_BIG (-1e30f)

typedef short short8 __attribute__((ext_vector_type(8)));
typedef float f32x4 __attribute__((ext_vector_type(4)));

__device__ __forceinline__ ushort f2bf(float x) {
    union { float f; unsigned u; } c; c.f = x;
    unsigned r = (c.u + 0x7FFFu + ((c.u >> 16) & 1u)) >> 16;
    return (ushort)r;
}

__device__ __forceinline__ f32x4 mfma16(short8 a, short8 b, f32x4 c) {
    return __builtin_amdgcn_mfma_f32_16x16x32_bf16(a, b, c, 0, 0, 0);
}

// ---------------------------------------------------------------------------
// Streaming fp32 -> bf16 convert (for q/k/v inputs).  n4 = elems/4.
// ---------------------------------------------------------------------------
__global__ __launch_bounds__(256) void cvt_kernel(
    const float* __restrict__ in, ushort* __restrict__ out, int n4) {
    int i = blockIdx.x * 256 + threadIdx.x;
    if (i < n4) {
        float4 x = reinterpret_cast<const float4*>(in)[i];
        ushort4 p;
        p.x = f2bf(x.x); p.y = f2bf(x.y); p.z = f2bf(x.z); p.w = f2bf(x.w);
        reinterpret_cast<ushort4*>(out)[i] = p;
    }
}

// ---------------------------------------------------------------------------
// Weight prep: in fp32 [K][N] (slice blockIdx.z) -> out bf16 [N][K].
// ---------------------------------------------------------------------------
__global__ __launch_bounds__(256) void wtrans_kernel(
    const float* __restrict__ in, ushort* __restrict__ out, int K, int N) {
    __shared__ float tile[32][33];
    const float* ins = in + (size_t)blockIdx.z * K * N;
    ushort* outs = out + (size_t)blockIdx.z * K * N;
    const int k0 = blockIdx.x * 32, n0 = blockIdx.y * 32;
    const int tx = threadIdx.x & 31, ty = threadIdx.x >> 5;  // 32 x 8
#pragma unroll
    for (int r = 0; r < 32; r += 8)
        tile[ty + r][tx] = ins[(size_t)(k0 + ty + r) * N + n0 + tx];
    __syncthreads();
#pragma unroll
    for (int r = 0; r < 32; r += 8)
        outs[(size_t)(n0 + ty + r) * K + k0 + tx] = f2bf(tile[tx][ty + r]);
}

// ---------------------------------------------------------------------------
// 128x128-tile bf16 MFMA projection: Xb bf16 [4096][1024] x Wt bf16 [n][k]
// (+bias, *oscale) -> bf16.  VMODE 0: out[z][s][64]; VMODE 1: out[z][64][s].
// grid 256 (XCD-swizzled), block 512 (8 waves, each 64x32 out).
// Double-buffered LDS, register prefetch, 1 barrier per K-step.
// ---------------------------------------------------------------------------
template <int VMODE>
__global__ __launch_bounds__(512) void proj_mfma_kernel(
    const ushort* __restrict__ Xb, const ushort* __restrict__ Wt,
    const float* __restrict__ bias, ushort* __restrict__ out, float oscale) {
    const int bid = blockIdx.x;
    const int w = (bid & 7) * 32 + (bid >> 3);  // XCD swizzle (256 = 8*32)
    const int mt = w >> 3, nt = w & 7;
    const int gm0 = mt * 128, n0 = nt * 128;
    const int t = threadIdx.x;
    const int wv = t >> 6, l = t & 63, j = l & 15, g = l >> 4;
    const int wm = wv >> 2, wn = wv & 3;

    __shared__ int4 Xs[2][1024];  // [128 rows][8 blk] XOR-swizzled
    __shared__ int4 Ws[2][1024];

    const f32x4 zf = {0.f, 0.f, 0.f, 0.f};
    f32x4 acc[4][2];
#pragma unroll
    for (int mm = 0; mm < 4; ++mm) { acc[mm][0] = zf; acc[mm][1] = zf; }

    const int rr0 = t >> 3, bb0 = t & 7;
    const int rr1 = (t + 512) >> 3, bb1 = t & 7;
    const int slot0 = rr0 * 8 + (bb0 ^ (rr0 & 7));
    const int slot1 = rr1 * 8 + (bb1 ^ (rr1 & 7));

    // prologue: stage K-step 0
    Xs[0][slot0] = *reinterpret_cast<const int4*>(Xb + (size_t)(gm0 + rr0) * D_ + bb0 * 8);
    Ws[0][slot0] = *reinterpret_cast<const int4*>(Wt + (size_t)(n0 + rr0) * D_ + bb0 * 8);
    Xs[0][slot1] = *reinterpret_cast<const int4*>(Xb + (size_t)(gm0 + rr1) * D_ + bb1 * 8);
    Ws[0][slot1] = *reinterpret_cast<const int4*>(Wt + (size_t)(n0 + rr1) * D_ + bb1 * 8);
    __syncthreads();

    for (int ks = 0; ks < 16; ++ks) {
        const int cur = ks & 1;
        const bool pf = (ks < 15);
        int4 xr0, wr0, xr1, wr1;
        if (pf) {
            const int k0n = (ks + 1) * 64;
            xr0 = *reinterpret_cast<const int4*>(Xb + (size_t)(gm0 + rr0) * D_ + k0n + bb0 * 8);
            wr0 = *reinterpret_cast<const int4*>(Wt + (size_t)(n0 + rr0) * D_ + k0n + bb0 * 8);
            xr1 = *reinterpret_cast<const int4*>(Xb + (size_t)(gm0 + rr1) * D_ + k0n + bb1 * 8);
            wr1 = *reinterpret_cast<const int4*>(Wt + (size_t)(n0 + rr1) * D_ + k0n + bb1 * 8);
        }

        __builtin_amdgcn_s_setprio(1);
#pragma unroll
        for (int eh = 0; eh < 2; ++eh) {
            short8 bfr[2];
#pragma unroll
            for (int nn = 0; nn < 2; ++nn) {
                int e = wn * 32 + nn * 16 + j;
                bfr[nn] = *reinterpret_cast<const short8*>(
                    &Ws[cur][e * 8 + ((eh * 4 + g) ^ (e & 7))]);
            }
#pragma unroll
            for (int mm = 0; mm < 4; ++mm) {
                int arow = wm * 64 + mm * 16 + j;
                short8 a = *reinterpret_cast<const short8*>(
                    &Xs[cur][arow * 8 + ((eh * 4 + g) ^ (arow & 7))]);
                acc[mm][0] = mfma16(a, bfr[0], acc[mm][0]);
                acc[mm][1] = mfma16(a, bfr[1], acc[mm][1]);
            }
        }
        __builtin_amdgcn_s_setprio(0);

        if (pf) {
            Xs[cur ^ 1][slot0] = xr0; Ws[cur ^ 1][slot0] = wr0;
            Xs[cur ^ 1][slot1] = xr1; Ws[cur ^ 1][slot1] = wr1;
        }
        __syncthreads();
    }

#pragma unroll
    for (int nn = 0; nn < 2; ++nn) {
        const int ncol = n0 + wn * 32 + nn * 16 + j;
        const int h = ncol >> 6, col = ncol & 63;
        const float bv = bias[ncol];
#pragma unroll
        for (int mm = 0; mm < 4; ++mm) {
            const int m = gm0 + wm * 64 + mm * 16 + g * 4;
            const int b = m >> 11, s = m & 2047;
            if (VMODE == 0) {
#pragma unroll
                for (int r = 0; r < 4; ++r)
                    out[((size_t)(b * H_ + h) * S_ + s + r) * E_ + col] =
                        f2bf((acc[mm][nn][r] + bv) * oscale);
            } else {
                ushort4 pk;
                pk.x = f2bf((acc[mm][nn][0] + bv) * oscale);
                pk.y = f2bf((acc[mm][nn][1] + bv) * oscale);
                pk.z = f2bf((acc[mm][nn][2] + bv) * oscale);
                pk.w = f2bf((acc[mm][nn][3] + bv) * oscale);
                *reinterpret_cast<ushort4*>(
                    &out[((size_t)(b * H_ + h) * E_ + col) * S_ + s]) = pk;
            }
        }
    }
}

// ---------------------------------------------------------------------------
// Fused attention, QBLK=128, 8 waves, two-pass softmax WITHOUT max tracking
// (scores bounded; exp2-domain folded into Q).  Double-buffered K/V staging.
// grid 512 blocks x 512 threads (XCD-swizzled).
// ---------------------------------------------------------------------------
__global__ __launch_bounds__(512) void attn_fused_kernel(
    const ushort* __restrict__ qh, const ushort* __restrict__ kh,
    const ushort* __restrict__ vt, float* __restrict__ wts,
    ushort* __restrict__ attnc) {
    const int f = blockIdx.x;
    const int xcd = f & 7, w = f >> 3;
    const int z = xcd * 4 + (w >> 4);
    const int qt = w & 15;
    const int q0 = qt * QBLK;
    const int ktmax = 2 * qt + 1;

    const int t = threadIdx.x;
    const int wv = t >> 6, l = t & 63, j = l & 15, g = l >> 4;

    const ushort* qhz = qh + (size_t)z * S_ * E_;
    const ushort* khz = kh + (size_t)z * S_ * E_;
    const ushort* vtz = vt + (size_t)z * E_ * S_;
    float* wz = wts + (size_t)z * S_ * S_;

    __shared__ int4 Kb[2][512];
    __shared__ int4 Vb[2][512];
    __shared__ __align__(16) ushort Ps[8][16][72];

    const int rr = t >> 3, bb = t & 7;
    const int lds_i = rr * 8 + (bb ^ (rr & 7));
    const int koff = rr * 64 + bb * 8;
    const int voff = rr * 2048 + bb * 8;

    short8 qf[2];
    {
        const ushort* qrow = qhz + (size_t)(q0 + wv * 16 + j) * E_;
        qf[0] = *reinterpret_cast<const short8*>(qrow + g * 8);
        qf[1] = *reinterpret_cast<const short8*>(qrow + 32 + g * 8);
    }
    const int qr_base = q0 + wv * 16 + g * 4;  // + r

    const f32x4 zf = {0.f, 0.f, 0.f, 0.f};
    float lsum[4] = {0.f, 0.f, 0.f, 0.f};

    // ---------------- phase 1: per-lane denominator (m = 0) -------------
    Kb[0][lds_i] = *reinterpret_cast<const int4*>(khz + koff);
    __syncthreads();
    for (int kt = 0; kt <= ktmax; ++kt) {
        const int cur = kt & 1;
        const bool pf = (kt < ktmax);
        int4 kreg;
        if (pf)
            kreg = *reinterpret_cast<const int4*>(khz + (kt + 1) * 4096 + koff);

        f32x4 sacc[4];
#pragma unroll
        for (int n = 0; n < 4; ++n) sacc[n] = zf;
        __builtin_amdgcn_s_setprio(1);
#pragma unroll
        for (int eh = 0; eh < 2; ++eh) {
#pragma unroll
            for (int n = 0; n < 4; ++n) {
                const int kc = n * 16 + j;
                short8 kf = *reinterpret_cast<const short8*>(
                    &Kb[cur][kc * 8 + ((eh * 4 + g) ^ (j & 7))]);
                sacc[n] = mfma16(qf[eh], kf, sacc[n]);
            }
        }
        __builtin_amdgcn_s_setprio(0);

        if (kt >= 2 * qt) {
#pragma unroll
            for (int n = 0; n < 4; ++n) {
                const int col = kt * 64 + n * 16 + j;
#pragma unroll
                for (int r = 0; r < 4; ++r)
                    if (col > qr_base + r) sacc[n][r] = NEG_BIG;
            }
        }
#pragma unroll
        for (int r = 0; r < 4; ++r)
            lsum[r] += (exp2f(sacc[0][r]) + exp2f(sacc[1][r])) +
                       (exp2f(sacc[2][r]) + exp2f(sacc[3][r]));

        if (pf) Kb[cur ^ 1][lds_i] = kreg;
        __syncthreads();
    }

    // one-time cross-lane merge (16 lanes j share a q-row)
    float invl[4];
#pragma unroll
    for (int r = 0; r < 4; ++r) {
        float tt = lsum[r];
        tt += __shfl_xor(tt, 1);
        tt += __shfl_xor(tt, 2);
        tt += __shfl_xor(tt, 4);
        tt += __shfl_xor(tt, 8);
        invl[r] = 1.0f / tt;
    }

    // ---------------- phase 2: recompute, write weights, PV -------------
    f32x4 oacc[4];
#pragma unroll
    for (int n = 0; n < 4; ++n) oacc[n] = zf;

    Kb[0][lds_i] = *reinterpret_cast<const int4*>(khz + koff);
    Vb[0][lds_i] = *reinterpret_cast<const int4*>(vtz + voff);
    __syncthreads();
    for (int kt = 0; kt <= ktmax; ++kt) {
        const int cur = kt & 1;
        const bool pf = (kt < ktmax);
        int4 kreg, vreg;
        if (pf) {
            kreg = *reinterpret_cast<const int4*>(khz + (kt + 1) * 4096 + koff);
            vreg = *reinterpret_cast<const int4*>(vtz + (kt + 1) * 64 + voff);
        }

        f32x4 sacc[4];
#pragma unroll
        for (int n = 0; n < 4; ++n) sacc[n] = zf;
        __builtin_amdgcn_s_setprio(1);
#pragma unroll
        for (int eh = 0; eh < 2; ++eh) {
#pragma unroll
            for (int n = 0; n < 4; ++n) {
                const int kc = n * 16 + j;
                short8 kf = *reinterpret_cast<const short8*>(
                    &Kb[cur][kc * 8 + ((eh * 4 + g) ^ (j & 7))]);
                sacc[n] = mfma16(qf[eh], kf, sacc[n]);
            }
        }
        __builtin_amdgcn_s_setprio(0);

        if (kt >= 2 * qt) {
#pragma unroll
            for (int n = 0; n < 4; ++n) {
                const int col = kt * 64 + n * 16 + j;
#pragma unroll
                for (int r = 0; r < 4; ++r)
                    if (col > qr_base + r) sacc[n][r] = NEG_BIG;
            }
        }

#pragma unroll
        for (int n = 0; n < 4; ++n) {
#pragma unroll
            for (int r = 0; r < 4; ++r) {
                float p = exp2f(sacc[n][r]) * invl[r];
                wz[(size_t)(qr_base + r) * S_ + kt * 64 + n * 16 + j] = p;
                Ps[wv][g * 4 + r][n * 16 + j] = f2bf(p);
            }
        }

        __builtin_amdgcn_s_setprio(1);
#pragma unroll
        for (int ks = 0; ks < 2; ++ks) {
            short8 pa =
                *reinterpret_cast<const short8*>(&Ps[wv][j][ks * 32 + g * 8]);
#pragma unroll
            for (int n = 0; n < 4; ++n) {
                const int e = n * 16 + j;
                short8 vb = *reinterpret_cast<const short8*>(
                    &Vb[cur][e * 8 + ((ks * 4 + g) ^ (j & 7))]);
                oacc[n] = mfma16(pa, vb, oacc[n]);
            }
        }
        __builtin_amdgcn_s_setprio(0);

        if (pf) {
            Kb[cur ^ 1][lds_i] = kreg;
            Vb[cur ^ 1][lds_i] = vreg;
        }
        __syncthreads();
    }

    // write attn bf16 in concat layout [b][s][h*64+e]
    {
        const int b = z >> 4, hh = z & 15;
#pragma unroll
        for (int n = 0; n < 4; ++n)
#pragma unroll
            for (int r = 0; r < 4; ++r)
                attnc[((size_t)(b * S_ + qr_base + r)) * D_ + hh * E_ +
                      n * 16 + j] = f2bf(oacc[n][r]);
    }

    // zero-fill the fully-masked (upper-triangle) weight columns
    const int c0 = q0 + QBLK;
    const int w4 = (S_ - c0) >> 2;
    if (w4 > 0) {
        const float4 z4 = make_float4(0.f, 0.f, 0.f, 0.f);
        for (int row = 0; row < QBLK; ++row) {
            float4* rp =
                reinterpret_cast<float4*>(wz + (size_t)(q0 + row) * S_ + c0);
            for (int c = t; c < w4; c += 512) rp[c] = z4;
        }
    }
}

// ---------------------------------------------------------------------------
// 128x128-tile out-projection: attnc bf16 [4096][1024] x Wot bf16 [n][k]
// + bo -> out fp32 [4096][1024].  grid 256 (XCD-swizzled), block 512.
// ---------------------------------------------------------------------------
__global__ __launch_bounds__(512) void outproj_mfma_kernel(
    const ushort* __restrict__ A, const ushort* __restrict__ Wot,
    const float* __restrict__ bo, float* __restrict__ out) {
    const int bid = blockIdx.x;
    const int w = (bid & 7) * 32 + (bid >> 3);
    const int mt = w >> 3, nt = w & 7;
    const int gm0 = mt * 128, n0 = nt * 128;
    const int t = threadIdx.x;
    const int wv = t >> 6, l = t & 63, j = l & 15, g = l >> 4;
    const int wm = wv >> 2, wn = wv & 3;

    __shared__ int4 As[2][1024];
    __shared__ int4 Bs[2][1024];

    const f32x4 zf = {0.f, 0.f, 0.f, 0.f};
    f32x4 acc[4][2];
#pragma unroll
    for (int mm = 0; mm < 4; ++mm) { acc[mm][0] = zf; acc[mm][1] = zf; }

    const int rr0 = t >> 3, bb0 = t & 7;
    const int rr1 = (t + 512) >> 3, bb1 = t & 7;
    const int slot0 = rr0 * 8 + (bb0 ^ (rr0 & 7));
    const int slot1 = rr1 * 8 + (bb1 ^ (rr1 & 7));

    As[0][slot0] = *reinterpret_cast<const int4*>(A + (size_t)(gm0 + rr0) * D_ + bb0 * 8);
    Bs[0][slot0] = *reinterpret_cast<const int4*>(Wot + (size_t)(n0 + rr0) * D_ + bb0 * 8);
    As[0][slot1] = *reinterpret_cast<const int4*>(A + (size_t)(gm0 + rr1) * D_ + bb1 * 8);
    Bs[0][slot1] = *reinterpret_cast<const int4*>(Wot + (size_t)(n0 + rr1) * D_ + bb1 * 8);
    __syncthreads();

    for (int ks = 0; ks < 16; ++ks) {
        const int cur = ks & 1;
        const bool pf = (ks < 15);
        int4 ar0, br0, ar1, br1;
        if (pf) {
            const int k0n = (ks + 1) * 64;
            ar0 = *reinterpret_cast<const int4*>(A + (size_t)(gm0 + rr0) * D_ + k0n + bb0 * 8);
            br0 = *reinterpret_cast<const int4*>(Wot + (size_t)(n0 + rr0) * D_ + k0n + bb0 * 8);
            ar1 = *reinterpret_cast<const int4*>(A + (size_t)(gm0 + rr1) * D_ + k0n + bb1 * 8);
            br1 = *reinterpret_cast<const int4*>(Wot + (size_t)(n0 + rr1) * D_ + k0n + bb1 * 8);
        }

        __builtin_amdgcn_s_setprio(1);
#pragma unroll
        for (int eh = 0; eh < 2; ++eh) {
            short8 bfr[2];
#pragma unroll
            for (int nn = 0; nn < 2; ++nn) {
                int e = wn * 32 + nn * 16 + j;
                bfr[nn] = *reinterpret_cast<const short8*>(
                    &Bs[cur][e * 8 + ((eh * 4 + g) ^ (e & 7))]);
            }
#pragma unroll
            for (int mm = 0; mm < 4; ++mm) {
                int arow = wm * 64 + mm * 16 + j;
                short8 a = *reinterpret_cast<const short8*>(
                    &As[cur][arow * 8 + ((eh * 4 + g) ^ (arow & 7))]);
                acc[mm][0] = mfma16(a, bfr[0], acc[mm][0]);
                acc[mm][1] = mfma16(a, bfr[1], acc[mm][1]);
            }
        }
        __builtin_amdgcn_s_setprio(0);

        if (pf) {
            As[cur ^ 1][slot0] = ar0; Bs[cur ^ 1][slot0] = br0;
            As[cur ^ 1][slot1] = ar1; Bs[cur ^ 1][slot1] = br1;
        }
        __syncthreads();
    }

#pragma unroll
    for (int nn = 0; nn < 2; ++nn) {
        const int ncol = n0 + wn * 32 + nn * 16 + j;
        const float bv = bo[ncol];
#pragma unroll
        for (int mm = 0; mm < 4; ++mm) {
            const int m = gm0 + wm * 64 + mm * 16 + g * 4;
#pragma unroll
            for (int r = 0; r < 4; ++r)
                out[(size_t)(m + r) * D_ + ncol] = acc[mm][nn][r] + bv;
        }
    }
}

// ---------------------------------------------------------------------------
extern "C" void kernel_launch(void* const* d_in, const int* in_sizes, int n_in,
                              void* d_out, int out_size, void* d_ws,
                              size_t ws_size, hipStream_t stream) {
    const float* q = (const float*)d_in[0];
    const float* k = (const float*)d_in[1];
    const float* v = (const float*)d_in[2];
    const float* Wq = (const float*)d_in[3];
    const float* bq = (const float*)d_in[4];
    const float* Wk = (const float*)d_in[5];
    const float* bk = (const float*)d_in[6];
    const float* Wv = (const float*)d_in[7];
    const float* bv = (const float*)d_in[8];
    const float* Wo = (const float*)d_in[9];
    const float* bo = (const float*)d_in[10];

    float* out = (float*)d_out;                    // [B,S,D]
    float* wts = out + (size_t)B_ * S_ * D_;       // [B,H,S,S]

    const size_t NZ = (size_t)Z_ * S_ * E_;        // 4,194,304
    const size_t NW = (size_t)H_ * E_ * D_;        // 1,048,576
    ushort* qh = (ushort*)d_ws;                    // bf16 [z][s][64] (scaled)
    ushort* kh = qh + NZ;                          // bf16 [z][s][64]
    ushort* vt = kh + NZ;                          // bf16 [z][64][s]
    ushort* attnc = vt + NZ;                       // bf16 [4096][1024] concat
    ushort* Wqt = attnc + NZ;                      // bf16 [h][64][1024]
    ushort* Wkt = Wqt + NW;
    ushort* Wvt = Wkt + NW;
    ushort* Wot = Wvt + NW;                        // bf16 [1024][1024] ([n][k])

    // bf16 copies of q/k/v staged in the (not-yet-written) wts region of
    // d_out: 3 x 8.4 MB << 537 MB; dead before attn_fused writes wts.
    ushort* xq = (ushort*)wts;
    ushort* xk = xq + NZ;
    ushort* xv = xk + NZ;

    const float QSCALE = 0.125f * 1.44269504088896340736f;  // 1/8 * log2(e)
    const int n4 = (int)(NZ / 4);

    dim3 b256(256), b512(512);
    cvt_kernel<<<dim3(4096), b256, 0, stream>>>(q, xq, n4);
    cvt_kernel<<<dim3(4096), b256, 0, stream>>>(k, xk, n4);
    cvt_kernel<<<dim3(4096), b256, 0, stream>>>(v, xv, n4);
    wtrans_kernel<<<dim3(32, 2, 16), b256, 0, stream>>>(Wq, Wqt, D_, E_);
    wtrans_kernel<<<dim3(32, 2, 16), b256, 0, stream>>>(Wk, Wkt, D_, E_);
    wtrans_kernel<<<dim3(32, 2, 16), b256, 0, stream>>>(Wv, Wvt, D_, E_);
    wtrans_kernel<<<dim3(32, 32, 1), b256, 0, stream>>>(Wo, Wot, D_, D_);
    proj_mfma_kernel<0><<<dim3(256), b512, 0, stream>>>(xq, Wqt, bq, qh, QSCALE);
    proj_mfma_kernel<0><<<dim3(256), b512, 0, stream>>>(xk, Wkt, bk, kh, 1.0f);
    proj_mfma_kernel<1><<<dim3(256), b512, 0, stream>>>(xv, Wvt, bv, vt, 1.0f);
    attn_fused_kernel<<<dim3(512), b512, 0, stream>>>(qh, kh, vt, wts, attnc);
    outproj_mfma_kernel<<<dim3(256), b512, 0, stream>>>(attnc, Wot, bo, out);
}

// Round 6
// 242.979 us; speedup vs baseline: 7.0806x; 1.0603x over previous
//
#include <hip/hip_runtime.h>
#include <math.h>

#define B_ 2
#define S_ 2048
#define D_ 1024
#define H_ 16
#define E_ 64
#define Z_ (B_ * H_)
#define QBLK 128
#define NEG_BIG (-1e30f)

typedef short short8 __attribute__((ext_vector_type(8)));
typedef float f32x4 __attribute__((ext_vector_type(4)));

__device__ __forceinline__ ushort f2bf(float x) {
    union { float f; unsigned u; } c; c.f = x;
    unsigned r = (c.u + 0x7FFFu + ((c.u >> 16) & 1u)) >> 16;
    return (ushort)r;
}

__device__ __forceinline__ f32x4 mfma16(short8 a, short8 b, f32x4 c) {
    return __builtin_amdgcn_mfma_f32_16x16x32_bf16(a, b, c, 0, 0, 0);
}

// ---------------------------------------------------------------------------
// Streaming fp32 -> bf16 convert, 3 tensors in one launch. grid (4096, 3).
// ---------------------------------------------------------------------------
__global__ __launch_bounds__(256) void cvt3_kernel(
    const float* __restrict__ in0, const float* __restrict__ in1,
    const float* __restrict__ in2, ushort* __restrict__ out0,
    ushort* __restrict__ out1, ushort* __restrict__ out2, int n4) {
    const int which = blockIdx.y;
    const float* in = (which == 0) ? in0 : (which == 1) ? in1 : in2;
    ushort* out = (which == 0) ? out0 : (which == 1) ? out1 : out2;
    int i = blockIdx.x * 256 + threadIdx.x;
    if (i < n4) {
        float4 x = reinterpret_cast<const float4*>(in)[i];
        ushort4 p;
        p.x = f2bf(x.x); p.y = f2bf(x.y); p.z = f2bf(x.z); p.w = f2bf(x.w);
        reinterpret_cast<ushort4*>(out)[i] = p;
    }
}

// ---------------------------------------------------------------------------
// Weight prep (QKV): fp32 [K][N] slice -> bf16 [N][K].  grid (32, 2, 48):
// z = which*16 + head.
// ---------------------------------------------------------------------------
__global__ __launch_bounds__(256) void wtrans3_kernel(
    const float* __restrict__ w0, const float* __restrict__ w1,
    const float* __restrict__ w2, ushort* __restrict__ o0,
    ushort* __restrict__ o1, ushort* __restrict__ o2) {
    __shared__ float tile[32][33];
    const int zz = blockIdx.z;
    const int which = zz >> 4, h = zz & 15;
    const float* in = (which == 0) ? w0 : (which == 1) ? w1 : w2;
    ushort* out = (which == 0) ? o0 : (which == 1) ? o1 : o2;
    const int K = D_, N = E_;
    const float* ins = in + (size_t)h * K * N;
    ushort* outs = out + (size_t)h * K * N;
    const int k0 = blockIdx.x * 32, n0 = blockIdx.y * 32;
    const int tx = threadIdx.x & 31, ty = threadIdx.x >> 5;  // 32 x 8
#pragma unroll
    for (int r = 0; r < 32; r += 8)
        tile[ty + r][tx] = ins[(size_t)(k0 + ty + r) * N + n0 + tx];
    __syncthreads();
#pragma unroll
    for (int r = 0; r < 32; r += 8)
        outs[(size_t)(n0 + ty + r) * K + k0 + tx] = f2bf(tile[tx][ty + r]);
}

// Wo prep: fp32 [K][N] -> bf16 [N][K], grid (32, 32).
__global__ __launch_bounds__(256) void wtrans_kernel(
    const float* __restrict__ in, ushort* __restrict__ out, int K, int N) {
    __shared__ float tile[32][33];
    const int k0 = blockIdx.x * 32, n0 = blockIdx.y * 32;
    const int tx = threadIdx.x & 31, ty = threadIdx.x >> 5;
#pragma unroll
    for (int r = 0; r < 32; r += 8)
        tile[ty + r][tx] = in[(size_t)(k0 + ty + r) * N + n0 + tx];
    __syncthreads();
#pragma unroll
    for (int r = 0; r < 32; r += 8)
        out[(size_t)(n0 + ty + r) * K + k0 + tx] = f2bf(tile[tx][ty + r]);
}

// ---------------------------------------------------------------------------
// Fused Q+K+V 128x128-tile bf16 MFMA projection.  grid 768 x 512 threads.
// which = bid>>8 (0:q->qh scaled, 1:k->kh, 2:v->vt transposed).
// Double-buffered LDS, register prefetch, 1 barrier per K-step.
// ---------------------------------------------------------------------------
__global__ __launch_bounds__(512) void proj3_mfma_kernel(
    const ushort* __restrict__ xq, const ushort* __restrict__ xk,
    const ushort* __restrict__ xv, const ushort* __restrict__ Wqt,
    const ushort* __restrict__ Wkt, const ushort* __restrict__ Wvt,
    const float* __restrict__ bq, const float* __restrict__ bk,
    const float* __restrict__ bv, ushort* __restrict__ qh,
    ushort* __restrict__ kh, ushort* __restrict__ vt, float qscale) {
    const int bid = blockIdx.x;
    const int which = bid >> 8;
    const int inner = bid & 255;
    const ushort* Xb = (which == 0) ? xq : (which == 1) ? xk : xv;
    const ushort* Wt = (which == 0) ? Wqt : (which == 1) ? Wkt : Wvt;
    const float* bias = (which == 0) ? bq : (which == 1) ? bk : bv;
    ushort* out = (which == 0) ? qh : (which == 1) ? kh : vt;
    const float oscale = (which == 0) ? qscale : 1.0f;

    const int w = (inner & 7) * 32 + (inner >> 3);  // XCD swizzle
    const int mt = w >> 3, nt = w & 7;
    const int gm0 = mt * 128, n0 = nt * 128;
    const int t = threadIdx.x;
    const int wv = t >> 6, l = t & 63, j = l & 15, g = l >> 4;
    const int wm = wv >> 2, wn = wv & 3;

    __shared__ int4 Xs[2][1024];  // [128 rows][8 blk] XOR-swizzled
    __shared__ int4 Ws[2][1024];

    const f32x4 zf = {0.f, 0.f, 0.f, 0.f};
    f32x4 acc[4][2];
#pragma unroll
    for (int mm = 0; mm < 4; ++mm) { acc[mm][0] = zf; acc[mm][1] = zf; }

    const int rr0 = t >> 3, bb0 = t & 7;
    const int rr1 = (t + 512) >> 3, bb1 = t & 7;
    const int slot0 = rr0 * 8 + (bb0 ^ (rr0 & 7));
    const int slot1 = rr1 * 8 + (bb1 ^ (rr1 & 7));

    Xs[0][slot0] = *reinterpret_cast<const int4*>(Xb + (size_t)(gm0 + rr0) * D_ + bb0 * 8);
    Ws[0][slot0] = *reinterpret_cast<const int4*>(Wt + (size_t)(n0 + rr0) * D_ + bb0 * 8);
    Xs[0][slot1] = *reinterpret_cast<const int4*>(Xb + (size_t)(gm0 + rr1) * D_ + bb1 * 8);
    Ws[0][slot1] = *reinterpret_cast<const int4*>(Wt + (size_t)(n0 + rr1) * D_ + bb1 * 8);
    __syncthreads();

    for (int ks = 0; ks < 16; ++ks) {
        const int cur = ks & 1;
        const bool pf = (ks < 15);
        int4 xr0, wr0, xr1, wr1;
        if (pf) {
            const int k0n = (ks + 1) * 64;
            xr0 = *reinterpret_cast<const int4*>(Xb + (size_t)(gm0 + rr0) * D_ + k0n + bb0 * 8);
            wr0 = *reinterpret_cast<const int4*>(Wt + (size_t)(n0 + rr0) * D_ + k0n + bb0 * 8);
            xr1 = *reinterpret_cast<const int4*>(Xb + (size_t)(gm0 + rr1) * D_ + k0n + bb1 * 8);
            wr1 = *reinterpret_cast<const int4*>(Wt + (size_t)(n0 + rr1) * D_ + k0n + bb1 * 8);
        }

        __builtin_amdgcn_s_setprio(1);
#pragma unroll
        for (int eh = 0; eh < 2; ++eh) {
            short8 bfr[2];
#pragma unroll
            for (int nn = 0; nn < 2; ++nn) {
                int e = wn * 32 + nn * 16 + j;
                bfr[nn] = *reinterpret_cast<const short8*>(
                    &Ws[cur][e * 8 + ((eh * 4 + g) ^ (e & 7))]);
            }
#pragma unroll
            for (int mm = 0; mm < 4; ++mm) {
                int arow = wm * 64 + mm * 16 + j;
                short8 a = *reinterpret_cast<const short8*>(
                    &Xs[cur][arow * 8 + ((eh * 4 + g) ^ (arow & 7))]);
                acc[mm][0] = mfma16(a, bfr[0], acc[mm][0]);
                acc[mm][1] = mfma16(a, bfr[1], acc[mm][1]);
            }
        }
        __builtin_amdgcn_s_setprio(0);

        if (pf) {
            Xs[cur ^ 1][slot0] = xr0; Ws[cur ^ 1][slot0] = wr0;
            Xs[cur ^ 1][slot1] = xr1; Ws[cur ^ 1][slot1] = wr1;
        }
        __syncthreads();
    }

#pragma unroll
    for (int nn = 0; nn < 2; ++nn) {
        const int ncol = n0 + wn * 32 + nn * 16 + j;
        const int h = ncol >> 6, col = ncol & 63;
        const float bvv = bias[ncol];
#pragma unroll
        for (int mm = 0; mm < 4; ++mm) {
            const int m = gm0 + wm * 64 + mm * 16 + g * 4;
            const int b = m >> 11, s = m & 2047;
            if (which != 2) {
#pragma unroll
                for (int r = 0; r < 4; ++r)
                    out[((size_t)(b * H_ + h) * S_ + s + r) * E_ + col] =
                        f2bf((acc[mm][nn][r] + bvv) * oscale);
            } else {
                ushort4 pk;
                pk.x = f2bf(acc[mm][nn][0] + bvv);
                pk.y = f2bf(acc[mm][nn][1] + bvv);
                pk.z = f2bf(acc[mm][nn][2] + bvv);
                pk.w = f2bf(acc[mm][nn][3] + bvv);
                *reinterpret_cast<ushort4*>(
                    &out[((size_t)(b * H_ + h) * E_ + col) * S_ + s]) = pk;
            }
        }
    }
}

// ---------------------------------------------------------------------------
// Fused attention, QBLK=128, 8 waves, two-pass softmax WITHOUT max tracking
// (scores bounded; exp2-domain folded into Q).  Double-buffered K/V staging.
// grid 512 blocks x 512 threads (XCD-swizzled).
// ---------------------------------------------------------------------------
__global__ __launch_bounds__(512) void attn_fused_kernel(
    const ushort* __restrict__ qh, const ushort* __restrict__ kh,
    const ushort* __restrict__ vt, float* __restrict__ wts,
    ushort* __restrict__ attnc) {
    const int f = blockIdx.x;
    const int xcd = f & 7, w = f >> 3;
    const int z = xcd * 4 + (w >> 4);
    const int qt = w & 15;
    const int q0 = qt * QBLK;
    const int ktmax = 2 * qt + 1;

    const int t = threadIdx.x;
    const int wv = t >> 6, l = t & 63, j = l & 15, g = l >> 4;

    const ushort* qhz = qh + (size_t)z * S_ * E_;
    const ushort* khz = kh + (size_t)z * S_ * E_;
    const ushort* vtz = vt + (size_t)z * E_ * S_;
    float* wz = wts + (size_t)z * S_ * S_;

    __shared__ int4 Kb[2][512];
    __shared__ int4 Vb[2][512];
    __shared__ __align__(16) ushort Ps[8][16][72];

    const int rr = t >> 3, bb = t & 7;
    const int lds_i = rr * 8 + (bb ^ (rr & 7));
    const int koff = rr * 64 + bb * 8;
    const int voff = rr * 2048 + bb * 8;

    short8 qf[2];
    {
        const ushort* qrow = qhz + (size_t)(q0 + wv * 16 + j) * E_;
        qf[0] = *reinterpret_cast<const short8*>(qrow + g * 8);
        qf[1] = *reinterpret_cast<const short8*>(qrow + 32 + g * 8);
    }
    const int qr_base = q0 + wv * 16 + g * 4;  // + r

    const f32x4 zf = {0.f, 0.f, 0.f, 0.f};
    float lsum[4] = {0.f, 0.f, 0.f, 0.f};

    // ---------------- phase 1: per-lane denominator (m = 0) -------------
    Kb[0][lds_i] = *reinterpret_cast<const int4*>(khz + koff);
    __syncthreads();
    for (int kt = 0; kt <= ktmax; ++kt) {
        const int cur = kt & 1;
        const bool pf = (kt < ktmax);
        int4 kreg;
        if (pf)
            kreg = *reinterpret_cast<const int4*>(khz + (kt + 1) * 4096 + koff);

        f32x4 sacc[4];
#pragma unroll
        for (int n = 0; n < 4; ++n) sacc[n] = zf;
        __builtin_amdgcn_s_setprio(1);
#pragma unroll
        for (int eh = 0; eh < 2; ++eh) {
#pragma unroll
            for (int n = 0; n < 4; ++n) {
                const int kc = n * 16 + j;
                short8 kf = *reinterpret_cast<const short8*>(
                    &Kb[cur][kc * 8 + ((eh * 4 + g) ^ (j & 7))]);
                sacc[n] = mfma16(qf[eh], kf, sacc[n]);
            }
        }
        __builtin_amdgcn_s_setprio(0);

        if (kt >= 2 * qt) {
#pragma unroll
            for (int n = 0; n < 4; ++n) {
                const int col = kt * 64 + n * 16 + j;
#pragma unroll
                for (int r = 0; r < 4; ++r)
                    if (col > qr_base + r) sacc[n][r] = NEG_BIG;
            }
        }
#pragma unroll
        for (int r = 0; r < 4; ++r)
            lsum[r] += (exp2f(sacc[0][r]) + exp2f(sacc[1][r])) +
                       (exp2f(sacc[2][r]) + exp2f(sacc[3][r]));

        if (pf) Kb[cur ^ 1][lds_i] = kreg;
        __syncthreads();
    }

    // one-time cross-lane merge (16 lanes j share a q-row)
    float invl[4];
#pragma unroll
    for (int r = 0; r < 4; ++r) {
        float tt = lsum[r];
        tt += __shfl_xor(tt, 1);
        tt += __shfl_xor(tt, 2);
        tt += __shfl_xor(tt, 4);
        tt += __shfl_xor(tt, 8);
        invl[r] = 1.0f / tt;
    }

    // ---------------- phase 2: recompute, write weights, PV -------------
    f32x4 oacc[4];
#pragma unroll
    for (int n = 0; n < 4; ++n) oacc[n] = zf;

    Kb[0][lds_i] = *reinterpret_cast<const int4*>(khz + koff);
    Vb[0][lds_i] = *reinterpret_cast<const int4*>(vtz + voff);
    __syncthreads();
    for (int kt = 0; kt <= ktmax; ++kt) {
        const int cur = kt & 1;
        const bool pf = (kt < ktmax);
        int4 kreg, vreg;
        if (pf) {
            kreg = *reinterpret_cast<const int4*>(khz + (kt + 1) * 4096 + koff);
            vreg = *reinterpret_cast<const int4*>(vtz + (kt + 1) * 64 + voff);
        }

        f32x4 sacc[4];
#pragma unroll
        for (int n = 0; n < 4; ++n) sacc[n] = zf;
        __builtin_amdgcn_s_setprio(1);
#pragma unroll
        for (int eh = 0; eh < 2; ++eh) {
#pragma unroll
            for (int n = 0; n < 4; ++n) {
                const int kc = n * 16 + j;
                short8 kf = *reinterpret_cast<const short8*>(
                    &Kb[cur][kc * 8 + ((eh * 4 + g) ^ (j & 7))]);
                sacc[n] = mfma16(qf[eh], kf, sacc[n]);
            }
        }
        __builtin_amdgcn_s_setprio(0);

        if (kt >= 2 * qt) {
#pragma unroll
            for (int n = 0; n < 4; ++n) {
                const int col = kt * 64 + n * 16 + j;
#pragma unroll
                for (int r = 0; r < 4; ++r)
                    if (col > qr_base + r) sacc[n][r] = NEG_BIG;
            }
        }

#pragma unroll
        for (int n = 0; n < 4; ++n) {
#pragma unroll
            for (int r = 0; r < 4; ++r) {
                float p = exp2f(sacc[n][r]) * invl[r];
                wz[(size_t)(qr_base + r) * S_ + kt * 64 + n * 16 + j] = p;
                Ps[wv][g * 4 + r][n * 16 + j] = f2bf(p);
            }
        }

        __builtin_amdgcn_s_setprio(1);
#pragma unroll
        for (int ks = 0; ks < 2; ++ks) {
            short8 pa =
                *reinterpret_cast<const short8*>(&Ps[wv][j][ks * 32 + g * 8]);
#pragma unroll
            for (int n = 0; n < 4; ++n) {
                const int e = n * 16 + j;
                short8 vb = *reinterpret_cast<const short8*>(
                    &Vb[cur][e * 8 + ((ks * 4 + g) ^ (j & 7))]);
                oacc[n] = mfma16(pa, vb, oacc[n]);
            }
        }
        __builtin_amdgcn_s_setprio(0);

        if (pf) {
            Kb[cur ^ 1][lds_i] = kreg;
            Vb[cur ^ 1][lds_i] = vreg;
        }
        __syncthreads();
    }

    // write attn bf16 in concat layout [b][s][h*64+e]
    {
        const int b = z >> 4, hh = z & 15;
#pragma unroll
        for (int n = 0; n < 4; ++n)
#pragma unroll
            for (int r = 0; r < 4; ++r)
                attnc[((size_t)(b * S_ + qr_base + r)) * D_ + hh * E_ +
                      n * 16 + j] = f2bf(oacc[n][r]);
    }

    // zero-fill the fully-masked (upper-triangle) weight columns
    const int c0 = q0 + QBLK;
    const int w4 = (S_ - c0) >> 2;
    if (w4 > 0) {
        const float4 z4 = make_float4(0.f, 0.f, 0.f, 0.f);
        for (int row = 0; row < QBLK; ++row) {
            float4* rp =
                reinterpret_cast<float4*>(wz + (size_t)(q0 + row) * S_ + c0);
            for (int c = t; c < w4; c += 512) rp[c] = z4;
        }
    }
}

// ---------------------------------------------------------------------------
// 128x128-tile out-projection: attnc bf16 [4096][1024] x Wot bf16 [n][k]
// + bo -> out fp32 [4096][1024].  grid 256 (XCD-swizzled), block 512.
// ---------------------------------------------------------------------------
__global__ __launch_bounds__(512) void outproj_mfma_kernel(
    const ushort* __restrict__ A, const ushort* __restrict__ Wot,
    const float* __restrict__ bo, float* __restrict__ out) {
    const int bid = blockIdx.x;
    const int w = (bid & 7) * 32 + (bid >> 3);
    const int mt = w >> 3, nt = w & 7;
    const int gm0 = mt * 128, n0 = nt * 128;
    const int t = threadIdx.x;
    const int wv = t >> 6, l = t & 63, j = l & 15, g = l >> 4;
    const int wm = wv >> 2, wn = wv & 3;

    __shared__ int4 As[2][1024];
    __shared__ int4 Bs[2][1024];

    const f32x4 zf = {0.f, 0.f, 0.f, 0.f};
    f32x4 acc[4][2];
#pragma unroll
    for (int mm = 0; mm < 4; ++mm) { acc[mm][0] = zf; acc[mm][1] = zf; }

    const int rr0 = t >> 3, bb0 = t & 7;
    const int rr1 = (t + 512) >> 3, bb1 = t & 7;
    const int slot0 = rr0 * 8 + (bb0 ^ (rr0 & 7));
    const int slot1 = rr1 * 8 + (bb1 ^ (rr1 & 7));

    As[0][slot0] = *reinterpret_cast<const int4*>(A + (size_t)(gm0 + rr0) * D_ + bb0 * 8);
    Bs[0][slot0] = *reinterpret_cast<const int4*>(Wot + (size_t)(n0 + rr0) * D_ + bb0 * 8);
    As[0][slot1] = *reinterpret_cast<const int4*>(A + (size_t)(gm0 + rr1) * D_ + bb1 * 8);
    Bs[0][slot1] = *reinterpret_cast<const int4*>(Wot + (size_t)(n0 + rr1) * D_ + bb1 * 8);
    __syncthreads();

    for (int ks = 0; ks < 16; ++ks) {
        const int cur = ks & 1;
        const bool pf = (ks < 15);
        int4 ar0, br0, ar1, br1;
        if (pf) {
            const int k0n = (ks + 1) * 64;
            ar0 = *reinterpret_cast<const int4*>(A + (size_t)(gm0 + rr0) * D_ + k0n + bb0 * 8);
            br0 = *reinterpret_cast<const int4*>(Wot + (size_t)(n0 + rr0) * D_ + k0n + bb0 * 8);
            ar1 = *reinterpret_cast<const int4*>(A + (size_t)(gm0 + rr1) * D_ + k0n + bb1 * 8);
            br1 = *reinterpret_cast<const int4*>(Wot + (size_t)(n0 + rr1) * D_ + k0n + bb1 * 8);
        }

        __builtin_amdgcn_s_setprio(1);
#pragma unroll
        for (int eh = 0; eh < 2; ++eh) {
            short8 bfr[2];
#pragma unroll
            for (int nn = 0; nn < 2; ++nn) {
                int e = wn * 32 + nn * 16 + j;
                bfr[nn] = *reinterpret_cast<const short8*>(
                    &Bs[cur][e * 8 + ((eh * 4 + g) ^ (e & 7))]);
            }
#pragma unroll
            for (int mm = 0; mm < 4; ++mm) {
                int arow = wm * 64 + mm * 16 + j;
                short8 a = *reinterpret_cast<const short8*>(
                    &As[cur][arow * 8 + ((eh * 4 + g) ^ (arow & 7))]);
                acc[mm][0] = mfma16(a, bfr[0], acc[mm][0]);
                acc[mm][1] = mfma16(a, bfr[1], acc[mm][1]);
            }
        }
        __builtin_amdgcn_s_setprio(0);

        if (pf) {
            As[cur ^ 1][slot0] = ar0; Bs[cur ^ 1][slot0] = br0;
            As[cur ^ 1][slot1] = ar1; Bs[cur ^ 1][slot1] = br1;
        }
        __syncthreads();
    }

#pragma unroll
    for (int nn = 0; nn < 2; ++nn) {
        const int ncol = n0 + wn * 32 + nn * 16 + j;
        const float bvv = bo[ncol];
#pragma unroll
        for (int mm = 0; mm < 4; ++mm) {
            const int m = gm0 + wm * 64 + mm * 16 + g * 4;
#pragma unroll
            for (int r = 0; r < 4; ++r)
                out[(size_t)(m + r) * D_ + ncol] = acc[mm][nn][r] + bvv;
        }
    }
}

// ---------------------------------------------------------------------------
extern "C" void kernel_launch(void* const* d_in, const int* in_sizes, int n_in,
                              void* d_out, int out_size, void* d_ws,
                              size_t ws_size, hipStream_t stream) {
    const float* q = (const float*)d_in[0];
    const float* k = (const float*)d_in[1];
    const float* v = (const float*)d_in[2];
    const float* Wq = (const float*)d_in[3];
    const float* bq = (const float*)d_in[4];
    const float* Wk = (const float*)d_in[5];
    const float* bk = (const float*)d_in[6];
    const float* Wv = (const float*)d_in[7];
    const float* bv = (const float*)d_in[8];
    const float* Wo = (const float*)d_in[9];
    const float* bo = (const float*)d_in[10];

    float* out = (float*)d_out;                    // [B,S,D]
    float* wts = out + (size_t)B_ * S_ * D_;       // [B,H,S,S]

    const size_t NZ = (size_t)Z_ * S_ * E_;        // 4,194,304
    const size_t NW = (size_t)H_ * E_ * D_;        // 1,048,576
    ushort* qh = (ushort*)d_ws;                    // bf16 [z][s][64] (scaled)
    ushort* kh = qh + NZ;                          // bf16 [z][s][64]
    ushort* vt = kh + NZ;                          // bf16 [z][64][s]
    ushort* attnc = vt + NZ;                       // bf16 [4096][1024] concat
    ushort* Wqt = attnc + NZ;                      // bf16 [h][64][1024]
    ushort* Wkt = Wqt + NW;
    ushort* Wvt = Wkt + NW;
    ushort* Wot = Wvt + NW;                        // bf16 [1024][1024] ([n][k])

    // bf16 copies of q/k/v staged in the (not-yet-written) wts region of
    // d_out: 3 x 8.4 MB << 537 MB; dead before attn_fused writes wts.
    ushort* xq = (ushort*)wts;
    ushort* xk = xq + NZ;
    ushort* xv = xk + NZ;

    const float QSCALE = 0.125f * 1.44269504088896340736f;  // 1/8 * log2(e)
    const int n4 = (int)(NZ / 4);

    dim3 b256(256), b512(512);
    cvt3_kernel<<<dim3(4096, 3), b256, 0, stream>>>(q, k, v, xq, xk, xv, n4);
    wtrans3_kernel<<<dim3(32, 2, 48), b256, 0, stream>>>(Wq, Wk, Wv, Wqt, Wkt,
                                                         Wvt);
    wtrans_kernel<<<dim3(32, 32, 1), b256, 0, stream>>>(Wo, Wot, D_, D_);
    proj3_mfma_kernel<<<dim3(768), b512, 0, stream>>>(
        xq, xk, xv, Wqt, Wkt, Wvt, bq, bk, bv, qh, kh, vt, QSCALE);
    attn_fused_kernel<<<dim3(512), b512, 0, stream>>>(qh, kh, vt, wts, attnc);
    outproj_mfma_kernel<<<dim3(256), b512, 0, stream>>>(attnc, Wot, bo, out);
}